// Round 1
// baseline (672.542 us; speedup 1.0000x reference)
//
#include <hip/hip_runtime.h>
#include <math.h>

#define B_ 4
#define C_ 512
#define L_ 4096
#define H_ 8
#define DH_ 64
#define MLP_ 2048
#define BL_ (B_*L_)      // 16384
#define LK_ (L_+1)       // 4097

typedef _Float16 f16;
typedef _Float16 f16x8 __attribute__((ext_vector_type(8)));
typedef float f32x4 __attribute__((ext_vector_type(4)));

// ---------------------------------------------------------------- transposes
__global__ __launch_bounds__(256) void transpose_w(const float* __restrict__ W,
                                                   f16* __restrict__ Wt, int K, int N) {
  __shared__ float tile[32][33];
  int n0 = blockIdx.x * 32, k0 = blockIdx.y * 32;
  int tx = threadIdx.x & 31, ty = threadIdx.x >> 5;
#pragma unroll
  for (int i = 0; i < 4; ++i)
    tile[ty + i * 8][tx] = W[(size_t)(k0 + ty + i * 8) * N + n0 + tx];
  __syncthreads();
#pragma unroll
  for (int i = 0; i < 4; ++i)
    Wt[(size_t)(n0 + ty + i * 8) * K + k0 + tx] = (f16)tile[tx][ty + i * 8];
}

__global__ __launch_bounds__(256) void transpose_x(const float* __restrict__ x,
                                                   f16* __restrict__ xf) {
  __shared__ float tile[32][33];
  int b = blockIdx.z;
  int l0 = blockIdx.x * 32, c0 = blockIdx.y * 32;
  int tx = threadIdx.x & 31, ty = threadIdx.x >> 5;
#pragma unroll
  for (int i = 0; i < 4; ++i)
    tile[ty + i * 8][tx] = x[((size_t)b * C_ + c0 + ty + i * 8) * L_ + l0 + tx];
  __syncthreads();
#pragma unroll
  for (int i = 0; i < 4; ++i)
    xf[((size_t)b * L_ + l0 + ty + i * 8) * C_ + c0 + tx] = (f16)tile[tx][ty + i * 8];
}

// res = a + m -> transpose -> + x
__global__ __launch_bounds__(256) void final_add(const f16* __restrict__ a,
                                                 const float* __restrict__ m,
                                                 const float* __restrict__ x,
                                                 float* __restrict__ out) {
  __shared__ float tile[32][33];
  int b = blockIdx.z;
  int l0 = blockIdx.x * 32, c0 = blockIdx.y * 32;
  int tx = threadIdx.x & 31, ty = threadIdx.x >> 5;
#pragma unroll
  for (int i = 0; i < 4; ++i) {
    size_t idx = ((size_t)b * L_ + l0 + ty + i * 8) * C_ + c0 + tx;
    tile[ty + i * 8][tx] = (float)a[idx] + m[idx];
  }
  __syncthreads();
#pragma unroll
  for (int i = 0; i < 4; ++i) {
    size_t o = ((size_t)b * C_ + c0 + ty + i * 8) * L_ + l0 + tx;
    out[o] = tile[tx][ty + i * 8] + x[o];
  }
}

// ---------------------------------------------------------------- GEMM (MFMA)
// C[M,N] = A[M,K] @ Bt[N,K]^T ; epilogues:
//  0: +bias -> f32       1: tanh(+bias)+1 -> f16
//  2: gelu(+bias) -> f16 3: (no bias) / (Bot[row*8+col/64]+1e-6) -> f32
template <int EPI>
__global__ __launch_bounds__(256) void gemm_bt(const f16* __restrict__ A,
                                               const f16* __restrict__ Bt,
                                               const float* __restrict__ bias,
                                               float* __restrict__ Cf,
                                               f16* __restrict__ Ch,
                                               int M, int N, int K,
                                               const float* __restrict__ Bot) {
  __shared__ f16 As[128 * 32];
  __shared__ f16 Bs[128 * 32];
  const int tid = threadIdx.x;
  const int lane = tid & 63, wv = tid >> 6;
  const int wm = wv >> 1, wn = wv & 1;
  const int bm = blockIdx.x * 128, bn = blockIdx.y * 128;
  const int l15 = lane & 15, q = lane >> 4;

  f32x4 acc[4][4] = {};
  const int r0 = tid >> 2, r1 = (tid + 256) >> 2;  // rows 0..63 / 64..127
  const int kg = (tid & 3) * 8;

  const f16* pa0 = A + (size_t)(bm + r0) * K + kg;
  const f16* pa1 = A + (size_t)(bm + r1) * K + kg;
  const f16* pb0 = Bt + (size_t)(bn + r0) * K + kg;
  const f16* pb1 = Bt + (size_t)(bn + r1) * K + kg;

  for (int k0 = 0; k0 < K; k0 += 32) {
    int4 va0 = *(const int4*)(pa0 + k0);
    int4 va1 = *(const int4*)(pa1 + k0);
    int4 vb0 = *(const int4*)(pb0 + k0);
    int4 vb1 = *(const int4*)(pb1 + k0);
    __syncthreads();
    *(int4*)&As[r0 * 32 + kg] = va0;
    *(int4*)&As[r1 * 32 + kg] = va1;
    *(int4*)&Bs[r0 * 32 + kg] = vb0;
    *(int4*)&Bs[r1 * 32 + kg] = vb1;
    __syncthreads();
    f16x8 af[4], bfv[4];
#pragma unroll
    for (int i = 0; i < 4; ++i)
      af[i] = *(const f16x8*)&As[(wm * 64 + i * 16 + l15) * 32 + q * 8];
#pragma unroll
    for (int j = 0; j < 4; ++j)
      bfv[j] = *(const f16x8*)&Bs[(wn * 64 + j * 16 + l15) * 32 + q * 8];
#pragma unroll
    for (int i = 0; i < 4; ++i)
#pragma unroll
      for (int j = 0; j < 4; ++j)
        acc[i][j] = __builtin_amdgcn_mfma_f32_16x16x32_f16(af[i], bfv[j], acc[i][j], 0, 0, 0);
  }

#pragma unroll
  for (int j = 0; j < 4; ++j) {
    int col = bn + wn * 64 + j * 16 + l15;
    float bb = (EPI == 3) ? 0.f : bias[col];
#pragma unroll
    for (int i = 0; i < 4; ++i) {
      int rowb = bm + wm * 64 + i * 16 + q * 4;
#pragma unroll
      for (int r = 0; r < 4; ++r) {
        int row = rowb + r;
        float v = acc[i][j][r] + bb;
        size_t o = (size_t)row * N + col;
        if (EPI == 0) {
          Cf[o] = v;
        } else if (EPI == 1) {
          Ch[o] = (f16)(tanhf(v) + 1.0f);
        } else if (EPI == 2) {
          Ch[o] = (f16)(0.5f * v * (1.0f + erff(v * 0.70710678118f)));
        } else {
          Cf[o] = v / (Bot[(size_t)row * H_ + (col >> 6)] + 1e-6f);
        }
      }
    }
  }
}

// ---------------------------------------------------------------- LayerNorm
__global__ __launch_bounds__(256) void ln_rows(const float* __restrict__ X,
                                               const float* __restrict__ g,
                                               const float* __restrict__ bta,
                                               f16* __restrict__ Y) {
  int wv = threadIdx.x >> 6, lane = threadIdx.x & 63;
  size_t row = (size_t)blockIdx.x * 4 + wv;
  const float* xr = X + row * C_;
  float4 v0 = *(const float4*)(xr + lane * 8);
  float4 v1 = *(const float4*)(xr + lane * 8 + 4);
  float vals[8] = {v0.x, v0.y, v0.z, v0.w, v1.x, v1.y, v1.z, v1.w};
  float s = 0.f, s2 = 0.f;
#pragma unroll
  for (int j = 0; j < 8; ++j) { s += vals[j]; s2 += vals[j] * vals[j]; }
#pragma unroll
  for (int m_ = 1; m_ < 64; m_ <<= 1) { s += __shfl_xor(s, m_); s2 += __shfl_xor(s2, m_); }
  float mu = s * (1.f / C_);
  float var = s2 * (1.f / C_) - mu * mu;
  float rstd = rsqrtf(var + 1e-5f);
  f16x8 o;
#pragma unroll
  for (int j = 0; j < 8; ++j) {
    int c = lane * 8 + j;
    o[j] = (f16)((vals[j] - mu) * rstd * g[c] + bta[c]);
  }
  *(f16x8*)(Y + row * C_ + lane * 8) = o;
}

// ---------------------------------------------------------------- q_probe
__global__ __launch_bounds__(256) void qprobe_accum(const f16* __restrict__ Q,
                                                    float* __restrict__ qp) {
  int b = blockIdx.y, l0 = blockIdx.x * 256, t = threadIdx.x;
  float s0 = 0.f, s1 = 0.f;
  for (int l = 0; l < 256; ++l) {
    const f16* row = Q + ((size_t)b * L_ + l0 + l) * C_;
    s0 += (float)row[t];
    s1 += (float)row[t + 256];
  }
  atomicAdd(&qp[b * C_ + t], s0);
  atomicAdd(&qp[b * C_ + t + 256], s1);
}

// ---------------------------------------------------------------- score logits
__global__ __launch_bounds__(256) void logits_kernel(const f16* __restrict__ Kh,
                                                     const float* __restrict__ qp,
                                                     float* __restrict__ score) {
  int wv = threadIdx.x >> 6, lane = threadIdx.x & 63;
  int token = blockIdx.x * 4 + wv;  // b*L + l
  int b = token >> 12;
  int l = token & (L_ - 1);
  const f16* row = Kh + (size_t)token * C_;
  int h = lane >> 3, j0 = (lane & 7) * 8;
  const float* qph = qp + b * C_ + h * DH_ + j0;
  float p = 0.f;
#pragma unroll
  for (int j = 0; j < 8; ++j) p += qph[j] * (float)row[h * DH_ + j0 + j];
  p += __shfl_xor(p, 1); p += __shfl_xor(p, 2); p += __shfl_xor(p, 4);
  if ((lane & 7) == 0)
    score[((size_t)b * H_ + h) * LK_ + 1 + l] = p * (1.f / L_) * 0.125f;  // /L mean, /sqrt(64)
}

__global__ __launch_bounds__(256) void softmax_kernel(float* __restrict__ score) {
  int bh = blockIdx.x, t = threadIdx.x;
  float* s = score + (size_t)bh * LK_;
  __shared__ float red[256];
  float mx = 0.f;  // logit[0] == 0 participates
  for (int i = t; i < L_; i += 256) mx = fmaxf(mx, s[1 + i]);
  red[t] = mx; __syncthreads();
  for (int k = 128; k; k >>= 1) { if (t < k) red[t] = fmaxf(red[t], red[t + k]); __syncthreads(); }
  mx = red[0]; __syncthreads();
  float sum = (t == 0) ? expf(-mx) : 0.f;
  for (int i = t; i < L_; i += 256) { float e = expf(s[1 + i] - mx); s[1 + i] = e; sum += e; }
  red[t] = sum; __syncthreads();
  for (int k = 128; k; k >>= 1) { if (t < k) red[t] += red[t + k]; __syncthreads(); }
  float inv = 1.f / red[0];
  __syncthreads();
  for (int i = t; i < L_; i += 256) s[1 + i] *= inv;
  if (t == 0) s[0] = expf(-mx) * inv;
}

// ---------------------------------------------------------------- kv / ksum
__global__ __launch_bounds__(256) void ksum_init(const float* __restrict__ score,
                                                 const float* __restrict__ bkk,
                                                 float* __restrict__ ksum) {
  int i = blockIdx.x * 256 + threadIdx.x;  // 0..2047
  int bh = i >> 6, d = i & 63, h = bh & 7;
  float pk0 = tanhf(bkk[h * DH_ + d]) + 1.f;
  ksum[i] = score[(size_t)bh * LK_] * pk0;
}

__global__ __launch_bounds__(256) void kv_accum(const f16* __restrict__ phiK,
                                                const f16* __restrict__ Vh,
                                                const float* __restrict__ score,
                                                float* __restrict__ kv,
                                                float* __restrict__ ksum) {
  int bh = blockIdx.y, b = bh >> 3, h = bh & 7;
  int l0 = blockIdx.x * 64;
  __shared__ float pks[64][65];
  __shared__ float vs[64][65];
  int t = threadIdx.x;
#pragma unroll
  for (int i = 0; i < 16; ++i) {
    int idx = i * 256 + t;
    int l = idx >> 6, cc = idx & 63;
    size_t grow = ((size_t)b * L_ + l0 + l) * C_ + h * DH_ + cc;
    float w = score[(size_t)bh * LK_ + 1 + l0 + l];
    pks[l][cc] = w * (float)phiK[grow];
    vs[l][cc] = (float)Vh[grow];
  }
  __syncthreads();
  int dr = (t >> 4) * 4, ec = (t & 15) * 4;
  float acc[4][4] = {};
  float ks[4] = {0.f, 0.f, 0.f, 0.f};
  for (int l = 0; l < 64; ++l) {
    float p0 = pks[l][dr], p1 = pks[l][dr + 1], p2 = pks[l][dr + 2], p3 = pks[l][dr + 3];
    float w0 = vs[l][ec], w1 = vs[l][ec + 1], w2 = vs[l][ec + 2], w3 = vs[l][ec + 3];
    acc[0][0] += p0 * w0; acc[0][1] += p0 * w1; acc[0][2] += p0 * w2; acc[0][3] += p0 * w3;
    acc[1][0] += p1 * w0; acc[1][1] += p1 * w1; acc[1][2] += p1 * w2; acc[1][3] += p1 * w3;
    acc[2][0] += p2 * w0; acc[2][1] += p2 * w1; acc[2][2] += p2 * w2; acc[2][3] += p2 * w3;
    acc[3][0] += p3 * w0; acc[3][1] += p3 * w1; acc[3][2] += p3 * w2; acc[3][3] += p3 * w3;
    if ((t & 15) == 0) { ks[0] += p0; ks[1] += p1; ks[2] += p2; ks[3] += p3; }
  }
#pragma unroll
  for (int i = 0; i < 4; ++i)
#pragma unroll
    for (int j = 0; j < 4; ++j)
      atomicAdd(&kv[((size_t)bh * 64 + dr + i) * 64 + ec + j], acc[i][j]);
  if ((t & 15) == 0)
#pragma unroll
    for (int i = 0; i < 4; ++i) atomicAdd(&ksum[bh * 64 + dr + i], ks[i]);
}

// block-diagonal kv as Bt[N=512][K=512] per batch (f16)
__global__ __launch_bounds__(256) void build_bd(const float* __restrict__ kv,
                                                f16* __restrict__ BD) {
  size_t i = (size_t)blockIdx.x * 256 + threadIdx.x;  // over 4*512*512
  int b = (int)(i >> 18);
  int nk = (int)(i & 262143);
  int n = nk >> 9, k = nk & 511;
  int hn = n >> 6, hk = k >> 6;
  float v = (hn == hk) ? kv[(((size_t)b * H_ + hn) * 64 + (k & 63)) * 64 + (n & 63)] : 0.f;
  BD[i] = (f16)v;
}

// bottom[b*L*H]: phiQ . ksum per (token, head)
__global__ __launch_bounds__(256) void bottom_kernel(const f16* __restrict__ phiQ,
                                                     const float* __restrict__ ksum,
                                                     float* __restrict__ bot) {
  int wv = threadIdx.x >> 6, lane = threadIdx.x & 63;
  int token = blockIdx.x * 4 + wv;  // b*L + l
  int b = token >> 12;
  const f16* row = phiQ + (size_t)token * C_;
  int h = lane >> 3, j0 = (lane & 7) * 8;
  const float* ks = ksum + (b * H_ + h) * 64 + j0;
  float p = 0.f;
#pragma unroll
  for (int j = 0; j < 8; ++j) p += ks[j] * (float)row[h * DH_ + j0 + j];
  p += __shfl_xor(p, 1); p += __shfl_xor(p, 2); p += __shfl_xor(p, 4);
  if ((lane & 7) == 0) bot[(size_t)token * H_ + h] = p;
}

// ---------------------------------------------------------------- launch
extern "C" void kernel_launch(void* const* d_in, const int* in_sizes, int n_in,
                              void* d_out, int out_size, void* d_ws, size_t ws_size,
                              hipStream_t stream) {
  (void)in_sizes; (void)n_in; (void)out_size; (void)ws_size;
  const float* x     = (const float*)d_in[0];
  const float* Wq    = (const float*)d_in[1];
  const float* bq    = (const float*)d_in[2];
  const float* gq    = (const float*)d_in[3];
  const float* betaq = (const float*)d_in[4];
  const float* Wk    = (const float*)d_in[5];
  const float* bk    = (const float*)d_in[6];
  const float* gk    = (const float*)d_in[7];
  const float* betak = (const float*)d_in[8];
  const float* Wv    = (const float*)d_in[9];
  const float* bv    = (const float*)d_in[10];
  const float* gv    = (const float*)d_in[11];
  const float* betav = (const float*)d_in[12];
  const float* Wkq   = (const float*)d_in[13];
  const float* bkq   = (const float*)d_in[14];
  const float* Wkk   = (const float*)d_in[15];
  const float* bkk   = (const float*)d_in[16];
  const float* g_at  = (const float*)d_in[17];
  const float* b_at  = (const float*)d_in[18];
  const float* W1    = (const float*)d_in[19];
  const float* b1    = (const float*)d_in[20];
  const float* W2    = (const float*)d_in[21];
  const float* b2    = (const float*)d_in[22];
  float* out = (float*)d_out;

  char* ws = (char*)d_ws;
  size_t off = 0;
  auto alloc = [&](size_t bytes) -> void* {
    void* p = ws + off;
    off += (bytes + 255) & ~(size_t)255;
    return p;
  };
  f16* xf    = (f16*)alloc((size_t)BL_ * C_ * 2);   // later reused as phiQ
  f16* Qh    = (f16*)alloc((size_t)BL_ * C_ * 2);   // later reused as a
  f16* Kh    = (f16*)alloc((size_t)BL_ * C_ * 2);
  f16* Vh    = (f16*)alloc((size_t)BL_ * C_ * 2);
  f16* phiK  = (f16*)alloc((size_t)BL_ * C_ * 2);
  float* tmp = (float*)alloc((size_t)BL_ * C_ * 4); // gemm out / attn out / mlp out
  f16* h1    = (f16*)alloc((size_t)BL_ * MLP_ * 2);
  f16* WqT   = (f16*)alloc((size_t)C_ * C_ * 2);
  f16* WkT   = (f16*)alloc((size_t)C_ * C_ * 2);
  f16* WvT   = (f16*)alloc((size_t)C_ * C_ * 2);
  f16* WkqT  = (f16*)alloc((size_t)C_ * C_ * 2);
  f16* WkkT  = (f16*)alloc((size_t)C_ * C_ * 2);
  f16* W1T   = (f16*)alloc((size_t)C_ * MLP_ * 2);
  f16* W2T   = (f16*)alloc((size_t)MLP_ * C_ * 2);
  f16* BD    = (f16*)alloc((size_t)B_ * C_ * C_ * 2);
  float* score = (float*)alloc((size_t)B_ * H_ * LK_ * 4);
  float* qp    = (float*)alloc((size_t)B_ * C_ * 4);
  float* kv    = (float*)alloc((size_t)B_ * H_ * DH_ * DH_ * 4);
  float* ksum  = (float*)alloc((size_t)B_ * H_ * DH_ * 4);
  float* bot   = (float*)alloc((size_t)BL_ * H_ * 4);
  f16* phiQ = xf;
  f16* ah = Qh;
  float* mbuf = tmp;

  dim3 blk(256);

  // weight conversion / transpose to [N,K] f16
  transpose_w<<<dim3(C_ / 32, C_ / 32), blk, 0, stream>>>(Wq, WqT, C_, C_);
  transpose_w<<<dim3(C_ / 32, C_ / 32), blk, 0, stream>>>(Wk, WkT, C_, C_);
  transpose_w<<<dim3(C_ / 32, C_ / 32), blk, 0, stream>>>(Wv, WvT, C_, C_);
  transpose_w<<<dim3(C_ / 32, C_ / 32), blk, 0, stream>>>(Wkq, WkqT, C_, C_);
  transpose_w<<<dim3(C_ / 32, C_ / 32), blk, 0, stream>>>(Wkk, WkkT, C_, C_);
  transpose_w<<<dim3(MLP_ / 32, C_ / 32), blk, 0, stream>>>(W1, W1T, C_, MLP_);
  transpose_w<<<dim3(C_ / 32, MLP_ / 32), blk, 0, stream>>>(W2, W2T, MLP_, C_);

  transpose_x<<<dim3(L_ / 32, C_ / 32, B_), blk, 0, stream>>>(x, xf);

  // Q/K/V projections + LN
  gemm_bt<0><<<dim3(BL_ / 128, C_ / 128), blk, 0, stream>>>(xf, WqT, bq, tmp, nullptr, BL_, C_, C_, nullptr);
  ln_rows<<<BL_ / 4, blk, 0, stream>>>(tmp, gq, betaq, Qh);
  gemm_bt<0><<<dim3(BL_ / 128, C_ / 128), blk, 0, stream>>>(xf, WkT, bk, tmp, nullptr, BL_, C_, C_, nullptr);
  ln_rows<<<BL_ / 4, blk, 0, stream>>>(tmp, gk, betak, Kh);
  gemm_bt<0><<<dim3(BL_ / 128, C_ / 128), blk, 0, stream>>>(xf, WvT, bv, tmp, nullptr, BL_, C_, C_, nullptr);
  ln_rows<<<BL_ / 4, blk, 0, stream>>>(tmp, gv, betav, Vh);

  // q_probe (sums; /L applied in logits)
  hipMemsetAsync(qp, 0, (size_t)B_ * C_ * 4, stream);
  qprobe_accum<<<dim3(L_ / 256, B_), blk, 0, stream>>>(Qh, qp);

  // phi projections (tanh+1)
  gemm_bt<1><<<dim3(BL_ / 128, C_ / 128), blk, 0, stream>>>(Qh, WkqT, bkq, nullptr, phiQ, BL_, C_, C_, nullptr);
  gemm_bt<1><<<dim3(BL_ / 128, C_ / 128), blk, 0, stream>>>(Kh, WkkT, bkk, nullptr, phiK, BL_, C_, C_, nullptr);

  // softmax-reweighting scores
  logits_kernel<<<BL_ / 4, blk, 0, stream>>>(Kh, qp, score);
  softmax_kernel<<<B_ * H_, blk, 0, stream>>>(score);

  // kv and ksum
  hipMemsetAsync(kv, 0, (size_t)B_ * H_ * DH_ * DH_ * 4, stream);
  ksum_init<<<(B_ * H_ * DH_) / 256, blk, 0, stream>>>(score, bkk, ksum);
  kv_accum<<<dim3(L_ / 64, B_ * H_), blk, 0, stream>>>(phiK, Vh, score, kv, ksum);

  // attention out = (phiQ @ blockdiag(kv)) / (phiQ . ksum + 1e-6)
  build_bd<<<(B_ * C_ * C_) / 256, blk, 0, stream>>>(kv, BD);
  bottom_kernel<<<BL_ / 4, blk, 0, stream>>>(phiQ, ksum, bot);
  for (int b = 0; b < B_; ++b)
    gemm_bt<3><<<dim3(L_ / 128, C_ / 128), blk, 0, stream>>>(
        phiQ + (size_t)b * L_ * C_, BD + (size_t)b * C_ * C_, nullptr,
        tmp + (size_t)b * L_ * C_, nullptr, L_, C_, C_, bot + (size_t)b * L_ * H_);

  // a = LN(out)
  ln_rows<<<BL_ / 4, blk, 0, stream>>>(tmp, g_at, b_at, ah);

  // MLP
  gemm_bt<2><<<dim3(BL_ / 128, MLP_ / 128), blk, 0, stream>>>(ah, W1T, b1, nullptr, h1, BL_, MLP_, C_, nullptr);
  gemm_bt<0><<<dim3(BL_ / 128, C_ / 128), blk, 0, stream>>>(h1, W2T, b2, mbuf, nullptr, BL_, C_, MLP_, nullptr);

  // res = a + m ; out = res^T + x
  final_add<<<dim3(L_ / 32, C_ / 32, B_), blk, 0, stream>>>(ah, mbuf, x, out);
}

// Round 2
// 512.682 us; speedup vs baseline: 1.3118x; 1.3118x over previous
//
#include <hip/hip_runtime.h>
#include <math.h>

#define B_ 4
#define C_ 512
#define L_ 4096
#define H_ 8
#define DH_ 64
#define MLP_ 2048
#define BL_ (B_*L_)      // 16384
#define LK_ (L_+1)       // 4097

typedef _Float16 f16;
typedef _Float16 f16x8 __attribute__((ext_vector_type(8)));
typedef _Float16 f16x4 __attribute__((ext_vector_type(4)));
typedef float f32x4 __attribute__((ext_vector_type(4)));

// async global->LDS, 16B per lane (m97 pattern)
__device__ __forceinline__ void gl16(void* lds, const void* g) {
  __builtin_amdgcn_global_load_lds((const __attribute__((address_space(1))) void*)g,
                                   (__attribute__((address_space(3))) void*)lds,
                                   16, 0, 0);
}

// ---------------------------------------------------------------- transposes
__global__ __launch_bounds__(256) void transpose_w(const float* __restrict__ W,
                                                   f16* __restrict__ Wt, int K, int N) {
  __shared__ float tile[32][33];
  int n0 = blockIdx.x * 32, k0 = blockIdx.y * 32;
  int tx = threadIdx.x & 31, ty = threadIdx.x >> 5;
#pragma unroll
  for (int i = 0; i < 4; ++i)
    tile[ty + i * 8][tx] = W[(size_t)(k0 + ty + i * 8) * N + n0 + tx];
  __syncthreads();
#pragma unroll
  for (int i = 0; i < 4; ++i)
    Wt[(size_t)(n0 + ty + i * 8) * K + k0 + tx] = (f16)tile[tx][ty + i * 8];
}

__global__ __launch_bounds__(256) void transpose_x(const float* __restrict__ x,
                                                   f16* __restrict__ xf) {
  __shared__ float tile[32][33];
  int b = blockIdx.z;
  int l0 = blockIdx.x * 32, c0 = blockIdx.y * 32;
  int tx = threadIdx.x & 31, ty = threadIdx.x >> 5;
#pragma unroll
  for (int i = 0; i < 4; ++i)
    tile[ty + i * 8][tx] = x[((size_t)b * C_ + c0 + ty + i * 8) * L_ + l0 + tx];
  __syncthreads();
#pragma unroll
  for (int i = 0; i < 4; ++i)
    xf[((size_t)b * L_ + l0 + ty + i * 8) * C_ + c0 + tx] = (f16)tile[tx][ty + i * 8];
}

// res = a + m -> transpose -> + x
__global__ __launch_bounds__(256) void final_add(const f16* __restrict__ a,
                                                 const float* __restrict__ m,
                                                 const float* __restrict__ x,
                                                 float* __restrict__ out) {
  __shared__ float tile[32][33];
  int b = blockIdx.z;
  int l0 = blockIdx.x * 32, c0 = blockIdx.y * 32;
  int tx = threadIdx.x & 31, ty = threadIdx.x >> 5;
#pragma unroll
  for (int i = 0; i < 4; ++i) {
    size_t idx = ((size_t)b * L_ + l0 + ty + i * 8) * C_ + c0 + tx;
    tile[ty + i * 8][tx] = (float)a[idx] + m[idx];
  }
  __syncthreads();
#pragma unroll
  for (int i = 0; i < 4; ++i) {
    size_t o = ((size_t)b * C_ + c0 + ty + i * 8) * L_ + l0 + tx;
    out[o] = tile[tx][ty + i * 8] + x[o];
  }
}

// ---------------------------------------------------------------- GEMM (MFMA)
// C[M,N] = A[M,K] @ Bt[N,K]^T ; epilogues:
//  0: +bias -> f32       1: tanh(+bias)+1 -> f16  (via sigmoid identity)
//  2: gelu(+bias) -> f16 3: (no bias) / (Bot[row*8+col/64]+1e-6) -> f32
template <int EPI>
__global__ __launch_bounds__(256) void gemm_bt(const f16* __restrict__ A,
                                               const f16* __restrict__ Bt,
                                               const float* __restrict__ bias,
                                               float* __restrict__ Cf,
                                               f16* __restrict__ Ch,
                                               int M, int N, int K,
                                               const float* __restrict__ Bot,
                                               long long zA, long long zB,
                                               long long zC, long long zBot) {
  __shared__ f16 As[128 * 32];
  __shared__ f16 Bs[128 * 32];
  A += (size_t)blockIdx.z * zA;
  Bt += (size_t)blockIdx.z * zB;
  if (Cf) Cf += (size_t)blockIdx.z * zC;
  if (Ch) Ch += (size_t)blockIdx.z * zC;
  if (EPI == 3) Bot += (size_t)blockIdx.z * zBot;

  const int tid = threadIdx.x;
  const int lane = tid & 63, wv = tid >> 6;
  const int wm = wv >> 1, wn = wv & 1;
  const int bm = blockIdx.x * 128, bn = blockIdx.y * 128;
  const int l15 = lane & 15, q = lane >> 4;

  f32x4 acc[4][4] = {};
  const int r0 = tid >> 2, r1 = (tid + 256) >> 2;  // rows 0..63 / 64..127
  const int kg = (tid & 3) * 8;

  const f16* pa0 = A + (size_t)(bm + r0) * K + kg;
  const f16* pa1 = A + (size_t)(bm + r1) * K + kg;
  const f16* pb0 = Bt + (size_t)(bn + r0) * K + kg;
  const f16* pb1 = Bt + (size_t)(bn + r1) * K + kg;
  f16* la0 = &As[r0 * 32 + kg];
  f16* la1 = &As[r1 * 32 + kg];
  f16* lb0 = &Bs[r0 * 32 + kg];
  f16* lb1 = &Bs[r1 * 32 + kg];

  for (int k0 = 0; k0 < K; k0 += 32) {
    __syncthreads();                 // previous iter's ds_reads done
    gl16(la0, pa0 + k0);
    gl16(la1, pa1 + k0);
    gl16(lb0, pb0 + k0);
    gl16(lb1, pb1 + k0);
    __syncthreads();                 // drains vmcnt(0): LDS staged
    f16x8 af[4], bfv[4];
#pragma unroll
    for (int i = 0; i < 4; ++i)
      af[i] = *(const f16x8*)&As[(wm * 64 + i * 16 + l15) * 32 + q * 8];
#pragma unroll
    for (int j = 0; j < 4; ++j)
      bfv[j] = *(const f16x8*)&Bs[(wn * 64 + j * 16 + l15) * 32 + q * 8];
#pragma unroll
    for (int i = 0; i < 4; ++i)
#pragma unroll
      for (int j = 0; j < 4; ++j)
        acc[i][j] = __builtin_amdgcn_mfma_f32_16x16x32_f16(af[i], bfv[j], acc[i][j], 0, 0, 0);
  }

#pragma unroll
  for (int j = 0; j < 4; ++j) {
    int col = bn + wn * 64 + j * 16 + l15;
    float bb = (EPI == 3) ? 0.f : bias[col];
#pragma unroll
    for (int i = 0; i < 4; ++i) {
      int rowb = bm + wm * 64 + i * 16 + q * 4;
#pragma unroll
      for (int r = 0; r < 4; ++r) {
        int row = rowb + r;
        float v = acc[i][j][r] + bb;
        size_t o = (size_t)row * N + col;
        if (EPI == 0) {
          Cf[o] = v;
        } else if (EPI == 1) {
          // tanh(v)+1 == 2/(1+exp(-2v)) : finite for all v
          Ch[o] = (f16)(2.0f * __frcp_rn(1.0f + __expf(-2.0f * v)));
        } else if (EPI == 2) {
          Ch[o] = (f16)(0.5f * v * (1.0f + erff(v * 0.70710678118f)));
        } else {
          Cf[o] = v / (Bot[(size_t)row * H_ + (col >> 6)] + 1e-6f);
        }
      }
    }
  }
}

// ---------------------------------------------------------------- LayerNorm
__global__ __launch_bounds__(256) void ln_rows(const float* __restrict__ X,
                                               const float* __restrict__ g,
                                               const float* __restrict__ bta,
                                               f16* __restrict__ Y) {
  int wv = threadIdx.x >> 6, lane = threadIdx.x & 63;
  size_t row = (size_t)blockIdx.x * 4 + wv;
  const float* xr = X + row * C_;
  float4 v0 = *(const float4*)(xr + lane * 8);
  float4 v1 = *(const float4*)(xr + lane * 8 + 4);
  float vals[8] = {v0.x, v0.y, v0.z, v0.w, v1.x, v1.y, v1.z, v1.w};
  float s = 0.f, s2 = 0.f;
#pragma unroll
  for (int j = 0; j < 8; ++j) { s += vals[j]; s2 += vals[j] * vals[j]; }
#pragma unroll
  for (int m_ = 1; m_ < 64; m_ <<= 1) { s += __shfl_xor(s, m_); s2 += __shfl_xor(s2, m_); }
  float mu = s * (1.f / C_);
  float var = s2 * (1.f / C_) - mu * mu;
  float rstd = rsqrtf(var + 1e-5f);
  f16x8 o;
#pragma unroll
  for (int j = 0; j < 8; ++j) {
    int c = lane * 8 + j;
    o[j] = (f16)((vals[j] - mu) * rstd * g[c] + bta[c]);
  }
  *(f16x8*)(Y + row * C_ + lane * 8) = o;
}

// ---------------------------------------------------------------- q_probe
// 256 blocks x 64 rows; coalesced f16x8 row reads, LDS reduce, few atomics
__global__ __launch_bounds__(256) void qprobe2(const f16* __restrict__ Q,
                                               float* __restrict__ qp) {
  int blk = blockIdx.x;
  int b = blk >> 6;             // 64 blocks per batch
  int r0 = blk * 64;
  int t = threadIdx.x;
  int c8 = (t & 63) * 8, rg = t >> 6;
  float s[8] = {0.f, 0.f, 0.f, 0.f, 0.f, 0.f, 0.f, 0.f};
#pragma unroll
  for (int i = 0; i < 16; ++i) {
    const f16* row = Q + ((size_t)r0 + rg + i * 4) * C_ + c8;
    f16x8 v = *(const f16x8*)row;
#pragma unroll
    for (int j = 0; j < 8; ++j) s[j] += (float)v[j];
  }
  __shared__ float red[4][520];
#pragma unroll
  for (int j = 0; j < 8; ++j) red[rg][c8 + j] = s[j];
  __syncthreads();
  int c = t * 2;
  float a0 = red[0][c] + red[1][c] + red[2][c] + red[3][c];
  float a1 = red[0][c + 1] + red[1][c + 1] + red[2][c + 1] + red[3][c + 1];
  atomicAdd(&qp[b * C_ + c], a0);
  atomicAdd(&qp[b * C_ + c + 1], a1);
}

// ---------------------------------------------------------------- score logits
__global__ __launch_bounds__(256) void logits_kernel(const f16* __restrict__ Kh,
                                                     const float* __restrict__ qp,
                                                     float* __restrict__ score) {
  int wv = threadIdx.x >> 6, lane = threadIdx.x & 63;
  int token = blockIdx.x * 4 + wv;  // b*L + l
  int b = token >> 12;
  int l = token & (L_ - 1);
  const f16* row = Kh + (size_t)token * C_;
  int h = lane >> 3, j0 = (lane & 7) * 8;
  const float* qph = qp + b * C_ + h * DH_ + j0;
  float p = 0.f;
#pragma unroll
  for (int j = 0; j < 8; ++j) p += qph[j] * (float)row[h * DH_ + j0 + j];
  p += __shfl_xor(p, 1); p += __shfl_xor(p, 2); p += __shfl_xor(p, 4);
  if ((lane & 7) == 0)
    score[((size_t)b * H_ + h) * LK_ + 1 + l] = p * (1.f / L_) * 0.125f;  // /L mean, /sqrt(64)
}

__global__ __launch_bounds__(256) void softmax_kernel(float* __restrict__ score) {
  int bh = blockIdx.x, t = threadIdx.x;
  float* s = score + (size_t)bh * LK_;
  __shared__ float red[256];
  float mx = 0.f;  // logit[0] == 0 participates
  for (int i = t; i < L_; i += 256) mx = fmaxf(mx, s[1 + i]);
  red[t] = mx; __syncthreads();
  for (int k = 128; k; k >>= 1) { if (t < k) red[t] = fmaxf(red[t], red[t + k]); __syncthreads(); }
  mx = red[0]; __syncthreads();
  float sum = (t == 0) ? expf(-mx) : 0.f;
  for (int i = t; i < L_; i += 256) { float e = expf(s[1 + i] - mx); s[1 + i] = e; sum += e; }
  red[t] = sum; __syncthreads();
  for (int k = 128; k; k >>= 1) { if (t < k) red[t] += red[t + k]; __syncthreads(); }
  float inv = 1.f / red[0];
  __syncthreads();
  for (int i = t; i < L_; i += 256) s[1 + i] *= inv;
  if (t == 0) s[0] = expf(-mx) * inv;
}

// ---------------------------------------------------------------- kv / ksum
__global__ __launch_bounds__(256) void ksum_init(const float* __restrict__ score,
                                                 const float* __restrict__ bkk,
                                                 float* __restrict__ ksum) {
  int i = blockIdx.x * 256 + threadIdx.x;  // 0..2047
  int bh = i >> 6, d = i & 63, h = bh & 7;
  float pk0 = tanhf(bkk[h * DH_ + d]) + 1.f;
  ksum[i] = score[(size_t)bh * LK_] * pk0;
}

// kv partials: grid (16 parts, 32 bh), 256 thr. Each block: 256 l-rows.
// 8x8 register blocking per lane, per-wave 64x64 acc, LDS merge,
// coalesced partial write kvp[bh][part][e*64+d]. ksum via LDS + atomics.
#define PIDX(l, c) ((l) * 68 + (c))
#define AIDX(d, e) ((d) * 68 + (e) + ((((d) >> 3)) << 2))   // bank-skewed
__global__ __launch_bounds__(256, 2) void kv_part_kernel(const f16* __restrict__ phiK,
                                                         const f16* __restrict__ Vh,
                                                         const float* __restrict__ score,
                                                         float* __restrict__ kvp,
                                                         float* __restrict__ ksum) {
  __shared__ float sm0[4416];   // weighted phiK chunk  [64][68] / later accum
  __shared__ float sm1[4416];   // V chunk              [64][68] / later ksum red
  int bh = blockIdx.y, b = bh >> 3, h = bh & 7;
  int part = blockIdx.x;
  int l0 = part * 256;
  int t = threadIdx.x, lane = t & 63, wv = t >> 6;
  int R = (lane >> 3) * 8, Cc = (lane & 7) * 8;
  float acc[8][8] = {};
  float ks[8] = {0.f, 0.f, 0.f, 0.f, 0.f, 0.f, 0.f, 0.f};

  for (int c = 0; c < 4; ++c) {      // chunks of 64 l
    int lc = l0 + c * 64;
    __syncthreads();                 // prior chunk's reads done
#pragma unroll
    for (int p = 0; p < 4; ++p) {
      int l = p * 16 + (t >> 4);
      int c4 = (t & 15) * 4;
      size_t grow = ((size_t)b * L_ + lc + l) * C_ + h * DH_ + c4;
      float w = score[(size_t)bh * LK_ + 1 + lc + l];
      f16x4 pk = *(const f16x4*)(phiK + grow);
      f16x4 vvv = *(const f16x4*)(Vh + grow);
      sm0[PIDX(l, c4) + 0] = w * (float)pk[0];
      sm0[PIDX(l, c4) + 1] = w * (float)pk[1];
      sm0[PIDX(l, c4) + 2] = w * (float)pk[2];
      sm0[PIDX(l, c4) + 3] = w * (float)pk[3];
      sm1[PIDX(l, c4) + 0] = (float)vvv[0];
      sm1[PIDX(l, c4) + 1] = (float)vvv[1];
      sm1[PIDX(l, c4) + 2] = (float)vvv[2];
      sm1[PIDX(l, c4) + 3] = (float)vvv[3];
    }
    __syncthreads();
#pragma unroll
    for (int i = 0; i < 16; ++i) {   // wave wv owns rows wv*16..+15
      int ll = wv * 16 + i;
      float4 a0 = *(const float4*)&sm0[PIDX(ll, R)];
      float4 a1 = *(const float4*)&sm0[PIDX(ll, R + 4)];
      float4 b0 = *(const float4*)&sm1[PIDX(ll, Cc)];
      float4 b1 = *(const float4*)&sm1[PIDX(ll, Cc + 4)];
      float av[8] = {a0.x, a0.y, a0.z, a0.w, a1.x, a1.y, a1.z, a1.w};
      float bv2[8] = {b0.x, b0.y, b0.z, b0.w, b1.x, b1.y, b1.z, b1.w};
#pragma unroll
      for (int ii = 0; ii < 8; ++ii)
#pragma unroll
        for (int jj = 0; jj < 8; ++jj) acc[ii][jj] += av[ii] * bv2[jj];
      if ((lane & 7) == 0) {
#pragma unroll
        for (int ii = 0; ii < 8; ++ii) ks[ii] += av[ii];
      }
    }
  }

  __syncthreads();                   // done with staging buffers
  if ((lane & 7) == 0) {
#pragma unroll
    for (int i = 0; i < 8; ++i) sm1[wv * 64 + R + i] = ks[i];
  }
  // merge 4 per-wave accumulators into sm0 (accum layout, bank-skewed)
  for (int w = 0; w < 4; ++w) {
    if (wv == w) {
#pragma unroll
      for (int i = 0; i < 8; ++i) {
        float* p0 = &sm0[AIDX(R + i, Cc)];
        if (w == 0) {
          *(float4*)p0 = make_float4(acc[i][0], acc[i][1], acc[i][2], acc[i][3]);
          *(float4*)(p0 + 4) = make_float4(acc[i][4], acc[i][5], acc[i][6], acc[i][7]);
        } else {
          float4 o0 = *(const float4*)p0, o1 = *(const float4*)(p0 + 4);
          o0.x += acc[i][0]; o0.y += acc[i][1]; o0.z += acc[i][2]; o0.w += acc[i][3];
          o1.x += acc[i][4]; o1.y += acc[i][5]; o1.z += acc[i][6]; o1.w += acc[i][7];
          *(float4*)p0 = o0;
          *(float4*)(p0 + 4) = o1;
        }
      }
    }
    __syncthreads();
  }
  if (t < 64) {
    float s = sm1[t] + sm1[64 + t] + sm1[128 + t] + sm1[192 + t];
    atomicAdd(&ksum[bh * 64 + t], s);
  }
  // partial kv, stored transposed: kvp[bh][part][e*64+d]
  float* dst = kvp + ((size_t)bh * 16 + part) * 4096;
#pragma unroll
  for (int i = 0; i < 16; ++i) {
    int idx = i * 256 + t;           // idx = e*64+d
    dst[idx] = sm0[AIDX(idx & 63, idx >> 6)];
  }
}

// block-diagonal kv as Bt[N=512][K=512] per batch (f16), summing 16 partials
__global__ __launch_bounds__(256) void build_bd(const float* __restrict__ kvp,
                                                f16* __restrict__ BD) {
  size_t i = (size_t)blockIdx.x * 256 + threadIdx.x;  // over 4*512*512
  int b = (int)(i >> 18);
  int nk = (int)(i & 262143);
  int n = nk >> 9, k = nk & 511;
  int hn = n >> 6, hk = k >> 6;
  float v = 0.f;
  if (hn == hk) {
    const float* p = kvp + ((size_t)(b * H_ + hn) * 16) * 4096 + (n & 63) * 64 + (k & 63);
#pragma unroll
    for (int pp = 0; pp < 16; ++pp) v += p[pp * 4096];
  }
  BD[i] = (f16)v;
}

// bottom[b*L*H]: phiQ . ksum per (token, head)
__global__ __launch_bounds__(256) void bottom_kernel(const f16* __restrict__ phiQ,
                                                     const float* __restrict__ ksum,
                                                     float* __restrict__ bot) {
  int wv = threadIdx.x >> 6, lane = threadIdx.x & 63;
  int token = blockIdx.x * 4 + wv;  // b*L + l
  int b = token >> 12;
  const f16* row = phiQ + (size_t)token * C_;
  int h = lane >> 3, j0 = (lane & 7) * 8;
  const float* ks = ksum + (b * H_ + h) * 64 + j0;
  float p = 0.f;
#pragma unroll
  for (int j = 0; j < 8; ++j) p += ks[j] * (float)row[h * DH_ + j0 + j];
  p += __shfl_xor(p, 1); p += __shfl_xor(p, 2); p += __shfl_xor(p, 4);
  if ((lane & 7) == 0) bot[(size_t)token * H_ + h] = p;
}

// ---------------------------------------------------------------- launch
extern "C" void kernel_launch(void* const* d_in, const int* in_sizes, int n_in,
                              void* d_out, int out_size, void* d_ws, size_t ws_size,
                              hipStream_t stream) {
  (void)in_sizes; (void)n_in; (void)out_size; (void)ws_size;
  const float* x     = (const float*)d_in[0];
  const float* Wq    = (const float*)d_in[1];
  const float* bq    = (const float*)d_in[2];
  const float* gq    = (const float*)d_in[3];
  const float* betaq = (const float*)d_in[4];
  const float* Wk    = (const float*)d_in[5];
  const float* bk    = (const float*)d_in[6];
  const float* gk    = (const float*)d_in[7];
  const float* betak = (const float*)d_in[8];
  const float* Wv    = (const float*)d_in[9];
  const float* bv    = (const float*)d_in[10];
  const float* gv    = (const float*)d_in[11];
  const float* betav = (const float*)d_in[12];
  const float* Wkq   = (const float*)d_in[13];
  const float* bkq   = (const float*)d_in[14];
  const float* Wkk   = (const float*)d_in[15];
  const float* bkk   = (const float*)d_in[16];
  const float* g_at  = (const float*)d_in[17];
  const float* b_at  = (const float*)d_in[18];
  const float* W1    = (const float*)d_in[19];
  const float* b1    = (const float*)d_in[20];
  const float* W2    = (const float*)d_in[21];
  const float* b2    = (const float*)d_in[22];
  float* out = (float*)d_out;

  char* ws = (char*)d_ws;
  size_t off = 0;
  auto alloc = [&](size_t bytes) -> void* {
    void* p = ws + off;
    off += (bytes + 255) & ~(size_t)255;
    return p;
  };
  f16* xf    = (f16*)alloc((size_t)BL_ * C_ * 2);   // later reused as phiQ
  f16* Qh    = (f16*)alloc((size_t)BL_ * C_ * 2);   // later reused as a
  f16* Kh    = (f16*)alloc((size_t)BL_ * C_ * 2);
  f16* Vh    = (f16*)alloc((size_t)BL_ * C_ * 2);
  f16* phiK  = (f16*)alloc((size_t)BL_ * C_ * 2);
  float* tmp = (float*)alloc((size_t)BL_ * C_ * 4); // gemm out / attn out / mlp out
  f16* h1    = (f16*)alloc((size_t)BL_ * MLP_ * 2);
  f16* WqT   = (f16*)alloc((size_t)C_ * C_ * 2);
  f16* WkT   = (f16*)alloc((size_t)C_ * C_ * 2);
  f16* WvT   = (f16*)alloc((size_t)C_ * C_ * 2);
  f16* WkqT  = (f16*)alloc((size_t)C_ * C_ * 2);
  f16* WkkT  = (f16*)alloc((size_t)C_ * C_ * 2);
  f16* W1T   = (f16*)alloc((size_t)C_ * MLP_ * 2);
  f16* W2T   = (f16*)alloc((size_t)MLP_ * C_ * 2);
  f16* BD    = (f16*)alloc((size_t)B_ * C_ * C_ * 2);
  float* score = (float*)alloc((size_t)B_ * H_ * LK_ * 4);
  float* qp    = (float*)alloc((size_t)B_ * C_ * 4);
  float* kvp   = (float*)alloc((size_t)B_ * H_ * 16 * 4096 * 4);  // 8 MB partials
  float* ksum  = (float*)alloc((size_t)B_ * H_ * DH_ * 4);
  float* bot   = (float*)alloc((size_t)BL_ * H_ * 4);
  f16* phiQ = xf;
  f16* ah = Qh;
  float* mbuf = tmp;

  dim3 blk(256);

  // weight conversion / transpose to [N,K] f16
  transpose_w<<<dim3(C_ / 32, C_ / 32), blk, 0, stream>>>(Wq, WqT, C_, C_);
  transpose_w<<<dim3(C_ / 32, C_ / 32), blk, 0, stream>>>(Wk, WkT, C_, C_);
  transpose_w<<<dim3(C_ / 32, C_ / 32), blk, 0, stream>>>(Wv, WvT, C_, C_);
  transpose_w<<<dim3(C_ / 32, C_ / 32), blk, 0, stream>>>(Wkq, WkqT, C_, C_);
  transpose_w<<<dim3(C_ / 32, C_ / 32), blk, 0, stream>>>(Wkk, WkkT, C_, C_);
  transpose_w<<<dim3(MLP_ / 32, C_ / 32), blk, 0, stream>>>(W1, W1T, C_, MLP_);
  transpose_w<<<dim3(C_ / 32, MLP_ / 32), blk, 0, stream>>>(W2, W2T, MLP_, C_);

  transpose_x<<<dim3(L_ / 32, C_ / 32, B_), blk, 0, stream>>>(x, xf);

  // Q/K/V projections + LN
  gemm_bt<0><<<dim3(BL_ / 128, C_ / 128), blk, 0, stream>>>(xf, WqT, bq, tmp, nullptr, BL_, C_, C_, nullptr, 0, 0, 0, 0);
  ln_rows<<<BL_ / 4, blk, 0, stream>>>(tmp, gq, betaq, Qh);
  gemm_bt<0><<<dim3(BL_ / 128, C_ / 128), blk, 0, stream>>>(xf, WkT, bk, tmp, nullptr, BL_, C_, C_, nullptr, 0, 0, 0, 0);
  ln_rows<<<BL_ / 4, blk, 0, stream>>>(tmp, gk, betak, Kh);
  gemm_bt<0><<<dim3(BL_ / 128, C_ / 128), blk, 0, stream>>>(xf, WvT, bv, tmp, nullptr, BL_, C_, C_, nullptr, 0, 0, 0, 0);
  ln_rows<<<BL_ / 4, blk, 0, stream>>>(tmp, gv, betav, Vh);

  // q_probe (sums; /L applied in logits)
  hipMemsetAsync(qp, 0, (size_t)B_ * C_ * 4, stream);
  qprobe2<<<BL_ / 64, blk, 0, stream>>>(Qh, qp);

  // phi projections (tanh+1)
  gemm_bt<1><<<dim3(BL_ / 128, C_ / 128), blk, 0, stream>>>(Qh, WkqT, bkq, nullptr, phiQ, BL_, C_, C_, nullptr, 0, 0, 0, 0);
  gemm_bt<1><<<dim3(BL_ / 128, C_ / 128), blk, 0, stream>>>(Kh, WkkT, bkk, nullptr, phiK, BL_, C_, C_, nullptr, 0, 0, 0, 0);

  // softmax-reweighting scores
  logits_kernel<<<BL_ / 4, blk, 0, stream>>>(Kh, qp, score);
  softmax_kernel<<<B_ * H_, blk, 0, stream>>>(score);

  // kv partials and ksum
  ksum_init<<<(B_ * H_ * DH_) / 256, blk, 0, stream>>>(score, bkk, ksum);
  kv_part_kernel<<<dim3(16, B_ * H_), blk, 0, stream>>>(phiK, Vh, score, kvp, ksum);

  // attention out = (phiQ @ blockdiag(kv)) / (phiQ . ksum + 1e-6)
  build_bd<<<(B_ * C_ * C_) / 256, blk, 0, stream>>>(kvp, BD);
  bottom_kernel<<<BL_ / 4, blk, 0, stream>>>(phiQ, ksum, bot);
  gemm_bt<3><<<dim3(L_ / 128, C_ / 128, B_), blk, 0, stream>>>(
      phiQ, BD, nullptr, tmp, nullptr, L_, C_, C_, bot,
      (long long)L_ * C_, (long long)C_ * C_, (long long)L_ * C_, (long long)L_ * H_);

  // a = LN(out)
  ln_rows<<<BL_ / 4, blk, 0, stream>>>(tmp, g_at, b_at, ah);

  // MLP
  gemm_bt<2><<<dim3(BL_ / 128, MLP_ / 128), blk, 0, stream>>>(ah, W1T, b1, nullptr, h1, BL_, MLP_, C_, nullptr, 0, 0, 0, 0);
  gemm_bt<0><<<dim3(BL_ / 128, C_ / 128), blk, 0, stream>>>(h1, W2T, b2, mbuf, nullptr, BL_, C_, MLP_, nullptr, 0, 0, 0, 0);

  // res = a + m ; out = res^T + x
  final_add<<<dim3(L_ / 32, C_ / 32, B_), blk, 0, stream>>>(ah, mbuf, x, out);
}

// Round 3
// 437.474 us; speedup vs baseline: 1.5373x; 1.1719x over previous
//
#include <hip/hip_runtime.h>
#include <math.h>

#define B_ 4
#define C_ 512
#define L_ 4096
#define H_ 8
#define DH_ 64
#define MLP_ 2048
#define BL_ (B_*L_)      // 16384
#define LK_ (L_+1)       // 4097

typedef _Float16 f16;
typedef _Float16 f16x8 __attribute__((ext_vector_type(8)));
typedef _Float16 f16x4 __attribute__((ext_vector_type(4)));
typedef float f32x4 __attribute__((ext_vector_type(4)));

// async global->LDS, 16B per lane (m97 pattern)
__device__ __forceinline__ void gl16(void* lds, const void* g) {
  __builtin_amdgcn_global_load_lds((const __attribute__((address_space(1))) void*)g,
                                   (__attribute__((address_space(3))) void*)lds,
                                   16, 0, 0);
}

__device__ __forceinline__ float frcp(float x) { return __builtin_amdgcn_rcpf(x); }

// ---------------------------------------------------------------- transposes
__global__ __launch_bounds__(256) void transpose_w(const float* __restrict__ W,
                                                   f16* __restrict__ Wt, int K, int N) {
  __shared__ float tile[32][33];
  int n0 = blockIdx.x * 32, k0 = blockIdx.y * 32;
  int tx = threadIdx.x & 31, ty = threadIdx.x >> 5;
#pragma unroll
  for (int i = 0; i < 4; ++i)
    tile[ty + i * 8][tx] = W[(size_t)(k0 + ty + i * 8) * N + n0 + tx];
  __syncthreads();
#pragma unroll
  for (int i = 0; i < 4; ++i)
    Wt[(size_t)(n0 + ty + i * 8) * K + k0 + tx] = (f16)tile[tx][ty + i * 8];
}

__global__ __launch_bounds__(256) void transpose_x(const float* __restrict__ x,
                                                   f16* __restrict__ xf) {
  __shared__ float tile[32][33];
  int b = blockIdx.z;
  int l0 = blockIdx.x * 32, c0 = blockIdx.y * 32;
  int tx = threadIdx.x & 31, ty = threadIdx.x >> 5;
#pragma unroll
  for (int i = 0; i < 4; ++i)
    tile[ty + i * 8][tx] = x[((size_t)b * C_ + c0 + ty + i * 8) * L_ + l0 + tx];
  __syncthreads();
#pragma unroll
  for (int i = 0; i < 4; ++i)
    xf[((size_t)b * L_ + l0 + ty + i * 8) * C_ + c0 + tx] = (f16)tile[tx][ty + i * 8];
}

// res = a + m -> transpose -> + x
__global__ __launch_bounds__(256) void final_add(const f16* __restrict__ a,
                                                 const f16* __restrict__ m,
                                                 const float* __restrict__ x,
                                                 float* __restrict__ out) {
  __shared__ float tile[32][33];
  int b = blockIdx.z;
  int l0 = blockIdx.x * 32, c0 = blockIdx.y * 32;
  int tx = threadIdx.x & 31, ty = threadIdx.x >> 5;
#pragma unroll
  for (int i = 0; i < 4; ++i) {
    size_t idx = ((size_t)b * L_ + l0 + ty + i * 8) * C_ + c0 + tx;
    tile[ty + i * 8][tx] = (float)a[idx] + (float)m[idx];
  }
  __syncthreads();
#pragma unroll
  for (int i = 0; i < 4; ++i) {
    size_t o = ((size_t)b * C_ + c0 + ty + i * 8) * L_ + l0 + tx;
    out[o] = tile[tx][ty + i * 8] + x[o];
  }
}

// ------------------------------------------------- pack small param vectors
__global__ __launch_bounds__(256) void pack_params(
    const float* bq, const float* bk, const float* bv,
    const float* gq, const float* gk, const float* gv,
    const float* betaq, const float* betak, const float* betav,
    const float* bkq, const float* bkk,
    float* bqkv, float* gqkv, float* betaqkv, float* bphi) {
  int i = blockIdx.x * 256 + threadIdx.x;  // 0..1535
  int w = i >> 9, c = i & 511;
  bqkv[i]    = (w == 0 ? bq : (w == 1 ? bk : bv))[c];
  gqkv[i]    = (w == 0 ? gq : (w == 1 ? gk : gv))[c];
  betaqkv[i] = (w == 0 ? betaq : (w == 1 ? betak : betav))[c];
  if (i < 1024) bphi[i] = (i < 512) ? bkq[i] : bkk[i - 512];
}

// ---------------------------------------------------------------- GEMM (MFMA)
// C[M,N](f16) = act(A[M,K] @ Bt[N,K]^T + bias)
// BK=64, XOR-swizzled k-chunks (conflict-free ds_read_b128),
// LDS-transposed coalesced f16 epilogue.
// EPI: 1 tanh(v)+1   2 gelu(v) (tanh approx)   3 v/(Bot+1e-6)   5 plain bias
template <int EPI>
__global__ __launch_bounds__(256) void gemm64(const f16* __restrict__ A,
                                              const f16* __restrict__ Bt,
                                              const float* __restrict__ bias,
                                              f16* __restrict__ Ch,
                                              int N, int K,
                                              const float* __restrict__ Bot,
                                              long long zA, long long zB,
                                              long long zC, long long zBias,
                                              long long zBot) {
  __shared__ f16 smem[2 * 128 * 64];   // As | Bs ; epilogue: [128][128] swizzled
  f16* As = smem;
  f16* Bs = smem + 128 * 64;
  A  += (size_t)blockIdx.z * zA;
  Bt += (size_t)blockIdx.z * zB;
  Ch += (size_t)blockIdx.z * zC;
  if (EPI == 3) Bot += (size_t)blockIdx.z * zBot;
  else          bias += (size_t)blockIdx.z * zBias;

  const int tid = threadIdx.x;
  const int lane = tid & 63, wv = tid >> 6;
  const int wm = wv >> 1, wn = wv & 1;
  const int bm = blockIdx.x * 128, bn = blockIdx.y * 128;
  const int l15 = lane & 15, q = lane >> 4;

  // staging map: inst p covers rows p*32+(tid>>3); lane fetches global chunk
  // (tid&7)^(row&7) into LDS slot tid*16B  -> LDS[r][c] holds global chunk c^(r&7)
  const int srow = tid >> 3;
  const int schunk = (tid & 7) ^ (srow & 7);
  const f16* pa = A + (size_t)(bm + srow) * K + schunk * 8;
  const f16* pb = Bt + (size_t)(bn + srow) * K + schunk * 8;
  f16* la = As + tid * 8;
  f16* lb = Bs + tid * 8;
  const int sw0 = (q ^ (lane & 7)) * 8;        // frag read swizzle, ks=0
  const int sw1 = ((4 + q) ^ (lane & 7)) * 8;  // ks=1

  f32x4 acc[4][4] = {};

  for (int k0 = 0; k0 < K; k0 += 64) {
    __syncthreads();                 // previous iter's ds_reads done
#pragma unroll
    for (int p = 0; p < 4; ++p) gl16(la + p * 2048, pa + (size_t)p * 32 * K + k0);
#pragma unroll
    for (int p = 0; p < 4; ++p) gl16(lb + p * 2048, pb + (size_t)p * 32 * K + k0);
    __syncthreads();                 // drains vmcnt(0): LDS staged
#pragma unroll
    for (int ks = 0; ks < 2; ++ks) {
      const int sw = ks ? sw1 : sw0;
      f16x8 af[4], bf[4];
#pragma unroll
      for (int i = 0; i < 4; ++i)
        af[i] = *(const f16x8*)&As[(wm * 64 + i * 16 + l15) * 64 + sw];
#pragma unroll
      for (int j = 0; j < 4; ++j)
        bf[j] = *(const f16x8*)&Bs[(wn * 64 + j * 16 + l15) * 64 + sw];
#pragma unroll
      for (int i = 0; i < 4; ++i)
#pragma unroll
        for (int j = 0; j < 4; ++j)
          acc[i][j] = __builtin_amdgcn_mfma_f32_16x16x32_f16(af[i], bf[j], acc[i][j], 0, 0, 0);
    }
  }

  // ---- epilogue: act -> smem (col-chunk XOR swizzle) -> coalesced f16x8 out
  __syncthreads();
#pragma unroll
  for (int j = 0; j < 4; ++j) {
    int lc = wn * 64 + j * 16 + l15;
    float bb = (EPI == 3) ? 0.f : bias[bn + lc];
#pragma unroll
    for (int i = 0; i < 4; ++i) {
#pragma unroll
      for (int r = 0; r < 4; ++r) {
        int lr = wm * 64 + i * 16 + q * 4 + r;
        float v = acc[i][j][r] + bb;
        if (EPI == 1) {
          v = 2.0f * frcp(1.0f + __expf(-2.0f * v));      // tanh(v)+1
        } else if (EPI == 2) {
          v = v * frcp(1.0f + __expf(-1.5957691f * (v + 0.044715f * v * v * v)));
        } else if (EPI == 3) {
          v = v * frcp(Bot[(size_t)(bm + lr) * H_ + ((bn + lc) >> 6)] + 1e-6f);
        }
        smem[lr * 128 + ((((lc >> 3) ^ (lr & 15)) << 3) | (lc & 7))] = (f16)v;
      }
    }
  }
  __syncthreads();
#pragma unroll
  for (int p = 0; p < 8; ++p) {
    int idx = p * 256 + tid;
    int row = idx >> 4, ch = idx & 15;
    f16x8 vv = *(const f16x8*)&smem[row * 128 + ((ch ^ (row & 15)) << 3)];
    *(f16x8*)&Ch[(size_t)(bm + row) * N + bn + ch * 8] = vv;
  }
}

// ---------------------------------------------------------------- LayerNorm (f16 in/out)
// threeway=1: X is [49152][512] rows (token*3+which); out which*BL + token.
__global__ __launch_bounds__(256) void ln16(const f16* __restrict__ X,
                                            const float* __restrict__ g,
                                            const float* __restrict__ bta,
                                            f16* __restrict__ Y, int threeway) {
  int wv = threadIdx.x >> 6, lane = threadIdx.x & 63;
  int r = blockIdx.x * 4 + wv;
  int token = r, which = 0;
  if (threeway) { token = r / 3; which = r - token * 3; }
  const f16* xr = X + (size_t)r * C_;
  f16x8 v = *(const f16x8*)(xr + lane * 8);
  float vals[8];
  float s = 0.f, s2 = 0.f;
#pragma unroll
  for (int j = 0; j < 8; ++j) { vals[j] = (float)v[j]; s += vals[j]; s2 += vals[j] * vals[j]; }
#pragma unroll
  for (int m_ = 1; m_ < 64; m_ <<= 1) { s += __shfl_xor(s, m_); s2 += __shfl_xor(s2, m_); }
  float mu = s * (1.f / C_);
  float var = s2 * (1.f / C_) - mu * mu;
  float rstd = rsqrtf(var + 1e-5f);
  const float* gp = g + which * C_;
  const float* bp = bta + which * C_;
  f16x8 o;
#pragma unroll
  for (int j = 0; j < 8; ++j) {
    int c = lane * 8 + j;
    o[j] = (f16)((vals[j] - mu) * rstd * gp[c] + bp[c]);
  }
  *(f16x8*)(Y + ((size_t)which * BL_ + token) * C_ + lane * 8) = o;
}

// ---------------------------------------------------------------- q_probe
__global__ __launch_bounds__(256) void qprobe2(const f16* __restrict__ Q,
                                               float* __restrict__ qp) {
  int blk = blockIdx.x;
  int b = blk >> 6;             // 64 blocks per batch
  int r0 = blk * 64;
  int t = threadIdx.x;
  int c8 = (t & 63) * 8, rg = t >> 6;
  float s[8] = {0.f, 0.f, 0.f, 0.f, 0.f, 0.f, 0.f, 0.f};
#pragma unroll
  for (int i = 0; i < 16; ++i) {
    const f16* row = Q + ((size_t)r0 + rg + i * 4) * C_ + c8;
    f16x8 v = *(const f16x8*)row;
#pragma unroll
    for (int j = 0; j < 8; ++j) s[j] += (float)v[j];
  }
  __shared__ float red[4][520];
#pragma unroll
  for (int j = 0; j < 8; ++j) red[rg][c8 + j] = s[j];
  __syncthreads();
  int c = t * 2;
  float a0 = red[0][c] + red[1][c] + red[2][c] + red[3][c];
  float a1 = red[0][c + 1] + red[1][c + 1] + red[2][c + 1] + red[3][c + 1];
  atomicAdd(&qp[b * C_ + c], a0);
  atomicAdd(&qp[b * C_ + c + 1], a1);
}

// ---------------------------------------------------------------- score logits
__global__ __launch_bounds__(256) void logits_kernel(const f16* __restrict__ Kh,
                                                     const float* __restrict__ qp,
                                                     float* __restrict__ score) {
  int wv = threadIdx.x >> 6, lane = threadIdx.x & 63;
  int token = blockIdx.x * 4 + wv;  // b*L + l
  int b = token >> 12;
  int l = token & (L_ - 1);
  const f16* row = Kh + (size_t)token * C_;
  int h = lane >> 3, j0 = (lane & 7) * 8;
  const float* qph = qp + b * C_ + h * DH_ + j0;
  float p = 0.f;
#pragma unroll
  for (int j = 0; j < 8; ++j) p += qph[j] * (float)row[h * DH_ + j0 + j];
  p += __shfl_xor(p, 1); p += __shfl_xor(p, 2); p += __shfl_xor(p, 4);
  if ((lane & 7) == 0)
    score[((size_t)b * H_ + h) * LK_ + 1 + l] = p * (1.f / L_) * 0.125f;  // /L mean, /sqrt(64)
}

__global__ __launch_bounds__(256) void softmax_kernel(float* __restrict__ score) {
  int bh = blockIdx.x, t = threadIdx.x;
  float* s = score + (size_t)bh * LK_;
  __shared__ float red[256];
  float mx = 0.f;  // logit[0] == 0 participates
  for (int i = t; i < L_; i += 256) mx = fmaxf(mx, s[1 + i]);
  red[t] = mx; __syncthreads();
  for (int k = 128; k; k >>= 1) { if (t < k) red[t] = fmaxf(red[t], red[t + k]); __syncthreads(); }
  mx = red[0]; __syncthreads();
  float sum = (t == 0) ? expf(-mx) : 0.f;
  for (int i = t; i < L_; i += 256) { float e = expf(s[1 + i] - mx); s[1 + i] = e; sum += e; }
  red[t] = sum; __syncthreads();
  for (int k = 128; k; k >>= 1) { if (t < k) red[t] += red[t + k]; __syncthreads(); }
  float inv = 1.f / red[0];
  __syncthreads();
  for (int i = t; i < L_; i += 256) s[1 + i] *= inv;
  if (t == 0) s[0] = expf(-mx) * inv;
}

// ---------------------------------------------------------------- kv / ksum
__global__ __launch_bounds__(256) void ksum_init(const float* __restrict__ score,
                                                 const float* __restrict__ bkk,
                                                 float* __restrict__ ksum) {
  int i = blockIdx.x * 256 + threadIdx.x;  // 0..2047
  int bh = i >> 6, d = i & 63, h = bh & 7;
  float pk0 = tanhf(bkk[h * DH_ + d]) + 1.f;
  ksum[i] = score[(size_t)bh * LK_] * pk0;
}

// kv partials: grid (16 parts, 32 bh), 256 thr. Each block: 256 l-rows.
#define PIDX(l, c) ((l) * 68 + (c))
#define AIDX(d, e) ((d) * 68 + (e) + ((((d) >> 3)) << 2))   // bank-skewed
__global__ __launch_bounds__(256, 2) void kv_part_kernel(const f16* __restrict__ phiK,
                                                         const f16* __restrict__ Vh,
                                                         const float* __restrict__ score,
                                                         float* __restrict__ kvp,
                                                         float* __restrict__ ksum) {
  __shared__ float sm0[4416];   // weighted phiK chunk  [64][68] / later accum
  __shared__ float sm1[4416];   // V chunk              [64][68] / later ksum red
  int bh = blockIdx.y, b = bh >> 3, h = bh & 7;
  int part = blockIdx.x;
  int l0 = part * 256;
  int t = threadIdx.x, lane = t & 63, wv = t >> 6;
  int R = (lane >> 3) * 8, Cc = (lane & 7) * 8;
  float acc[8][8] = {};
  float ks[8] = {0.f, 0.f, 0.f, 0.f, 0.f, 0.f, 0.f, 0.f};

  for (int c = 0; c < 4; ++c) {      // chunks of 64 l
    int lc = l0 + c * 64;
    __syncthreads();                 // prior chunk's reads done
#pragma unroll
    for (int p = 0; p < 4; ++p) {
      int l = p * 16 + (t >> 4);
      int c4 = (t & 15) * 4;
      size_t grow = ((size_t)b * L_ + lc + l) * C_ + h * DH_ + c4;
      float w = score[(size_t)bh * LK_ + 1 + lc + l];
      f16x4 pk = *(const f16x4*)(phiK + grow);
      f16x4 vvv = *(const f16x4*)(Vh + grow);
      sm0[PIDX(l, c4) + 0] = w * (float)pk[0];
      sm0[PIDX(l, c4) + 1] = w * (float)pk[1];
      sm0[PIDX(l, c4) + 2] = w * (float)pk[2];
      sm0[PIDX(l, c4) + 3] = w * (float)pk[3];
      sm1[PIDX(l, c4) + 0] = (float)vvv[0];
      sm1[PIDX(l, c4) + 1] = (float)vvv[1];
      sm1[PIDX(l, c4) + 2] = (float)vvv[2];
      sm1[PIDX(l, c4) + 3] = (float)vvv[3];
    }
    __syncthreads();
#pragma unroll
    for (int i = 0; i < 16; ++i) {   // wave wv owns rows wv*16..+15
      int ll = wv * 16 + i;
      float4 a0 = *(const float4*)&sm0[PIDX(ll, R)];
      float4 a1 = *(const float4*)&sm0[PIDX(ll, R + 4)];
      float4 b0 = *(const float4*)&sm1[PIDX(ll, Cc)];
      float4 b1 = *(const float4*)&sm1[PIDX(ll, Cc + 4)];
      float av[8] = {a0.x, a0.y, a0.z, a0.w, a1.x, a1.y, a1.z, a1.w};
      float bv2[8] = {b0.x, b0.y, b0.z, b0.w, b1.x, b1.y, b1.z, b1.w};
#pragma unroll
      for (int ii = 0; ii < 8; ++ii)
#pragma unroll
        for (int jj = 0; jj < 8; ++jj) acc[ii][jj] += av[ii] * bv2[jj];
      if ((lane & 7) == 0) {
#pragma unroll
        for (int ii = 0; ii < 8; ++ii) ks[ii] += av[ii];
      }
    }
  }

  __syncthreads();                   // done with staging buffers
  if ((lane & 7) == 0) {
#pragma unroll
    for (int i = 0; i < 8; ++i) sm1[wv * 64 + R + i] = ks[i];
  }
  for (int w = 0; w < 4; ++w) {
    if (wv == w) {
#pragma unroll
      for (int i = 0; i < 8; ++i) {
        float* p0 = &sm0[AIDX(R + i, Cc)];
        if (w == 0) {
          *(float4*)p0 = make_float4(acc[i][0], acc[i][1], acc[i][2], acc[i][3]);
          *(float4*)(p0 + 4) = make_float4(acc[i][4], acc[i][5], acc[i][6], acc[i][7]);
        } else {
          float4 o0 = *(const float4*)p0, o1 = *(const float4*)(p0 + 4);
          o0.x += acc[i][0]; o0.y += acc[i][1]; o0.z += acc[i][2]; o0.w += acc[i][3];
          o1.x += acc[i][4]; o1.y += acc[i][5]; o1.z += acc[i][6]; o1.w += acc[i][7];
          *(float4*)p0 = o0;
          *(float4*)(p0 + 4) = o1;
        }
      }
    }
    __syncthreads();
  }
  if (t < 64) {
    float s = sm1[t] + sm1[64 + t] + sm1[128 + t] + sm1[192 + t];
    atomicAdd(&ksum[bh * 64 + t], s);
  }
  float* dst = kvp + ((size_t)bh * 16 + part) * 4096;
#pragma unroll
  for (int i = 0; i < 16; ++i) {
    int idx = i * 256 + t;           // idx = e*64+d
    dst[idx] = sm0[AIDX(idx & 63, idx >> 6)];
  }
}

// block-diagonal kv as Bt[N=512][K=512] per batch (f16), summing 16 partials
__global__ __launch_bounds__(256) void build_bd(const float* __restrict__ kvp,
                                                f16* __restrict__ BD) {
  size_t i = (size_t)blockIdx.x * 256 + threadIdx.x;  // over 4*512*512
  int b = (int)(i >> 18);
  int nk = (int)(i & 262143);
  int n = nk >> 9, k = nk & 511;
  int hn = n >> 6, hk = k >> 6;
  float v = 0.f;
  if (hn == hk) {
    const float* p = kvp + ((size_t)(b * H_ + hn) * 16) * 4096 + (n & 63) * 64 + (k & 63);
#pragma unroll
    for (int pp = 0; pp < 16; ++pp) v += p[pp * 4096];
  }
  BD[i] = (f16)v;
}

// bottom[b*L*H]: phiQ . ksum per (token, head)
__global__ __launch_bounds__(256) void bottom_kernel(const f16* __restrict__ phiQ,
                                                     const float* __restrict__ ksum,
                                                     float* __restrict__ bot) {
  int wv = threadIdx.x >> 6, lane = threadIdx.x & 63;
  int token = blockIdx.x * 4 + wv;  // b*L + l
  int b = token >> 12;
  const f16* row = phiQ + (size_t)token * C_;
  int h = lane >> 3, j0 = (lane & 7) * 8;
  const float* ks = ksum + (b * H_ + h) * 64 + j0;
  float p = 0.f;
#pragma unroll
  for (int j = 0; j < 8; ++j) p += ks[j] * (float)row[h * DH_ + j0 + j];
  p += __shfl_xor(p, 1); p += __shfl_xor(p, 2); p += __shfl_xor(p, 4);
  if ((lane & 7) == 0) bot[(size_t)token * H_ + h] = p;
}

// ---------------------------------------------------------------- launch
extern "C" void kernel_launch(void* const* d_in, const int* in_sizes, int n_in,
                              void* d_out, int out_size, void* d_ws, size_t ws_size,
                              hipStream_t stream) {
  (void)in_sizes; (void)n_in; (void)out_size; (void)ws_size;
  const float* x     = (const float*)d_in[0];
  const float* Wq    = (const float*)d_in[1];
  const float* bq    = (const float*)d_in[2];
  const float* gq    = (const float*)d_in[3];
  const float* betaq = (const float*)d_in[4];
  const float* Wk    = (const float*)d_in[5];
  const float* bk    = (const float*)d_in[6];
  const float* gk    = (const float*)d_in[7];
  const float* betak = (const float*)d_in[8];
  const float* Wv    = (const float*)d_in[9];
  const float* bv    = (const float*)d_in[10];
  const float* gv    = (const float*)d_in[11];
  const float* betav = (const float*)d_in[12];
  const float* Wkq   = (const float*)d_in[13];
  const float* bkq   = (const float*)d_in[14];
  const float* Wkk   = (const float*)d_in[15];
  const float* bkk   = (const float*)d_in[16];
  const float* g_at  = (const float*)d_in[17];
  const float* b_at  = (const float*)d_in[18];
  const float* W1    = (const float*)d_in[19];
  const float* b1    = (const float*)d_in[20];
  const float* W2    = (const float*)d_in[21];
  const float* b2    = (const float*)d_in[22];
  float* out = (float*)d_out;

  char* ws = (char*)d_ws;
  size_t off = 0;
  auto alloc = [&](size_t bytes) -> void* {
    void* p = ws + off;
    off += (bytes + 255) & ~(size_t)255;
    return p;
  };
  // U1: tmpqkv(50MB) -> tmpA(16MB) -> h1(64MB), temporally disjoint
  f16* U1    = (f16*)alloc((size_t)BL_ * MLP_ * 2);       // 64 MB
  f16* QKVh  = (f16*)alloc((size_t)3 * BL_ * C_ * 2);     // 48 MB (Qh|Kh|Vh; ah reuses Qh)
  f16* phiQK = (f16*)alloc((size_t)2 * BL_ * C_ * 2);     // 32 MB (phiQ|phiK; mbuf reuses)
  f16* xf    = (f16*)alloc((size_t)BL_ * C_ * 2);         // 16 MB
  f16* WqkvT = (f16*)alloc((size_t)3 * C_ * C_ * 2);      // WqT|WkT|WvT contiguous
  f16* WkqT  = (f16*)alloc((size_t)C_ * C_ * 2);
  f16* WkkT  = (f16*)alloc((size_t)C_ * C_ * 2);          // adjacent to WkqT
  f16* W1T   = (f16*)alloc((size_t)C_ * MLP_ * 2);
  f16* W2T   = (f16*)alloc((size_t)MLP_ * C_ * 2);
  f16* BD    = (f16*)alloc((size_t)B_ * C_ * C_ * 2);
  float* score = (float*)alloc((size_t)B_ * H_ * LK_ * 4);
  float* qp    = (float*)alloc((size_t)B_ * C_ * 4);
  float* kvp   = (float*)alloc((size_t)B_ * H_ * 16 * 4096 * 4);
  float* ksum  = (float*)alloc((size_t)B_ * H_ * DH_ * 4);
  float* bot   = (float*)alloc((size_t)BL_ * H_ * 4);
  float* bqkv    = (float*)alloc(1536 * 4);
  float* gqkv    = (float*)alloc(1536 * 4);
  float* betaqkv = (float*)alloc(1536 * 4);
  float* bphi    = (float*)alloc(1024 * 4);

  f16* tmpqkv = U1;                  // [49152][512] f16
  f16* tmpA   = U1;                  // [16384][512] f16
  f16* h1     = U1;                  // [16384][2048] f16
  f16* Qh = QKVh;
  f16* Kh = QKVh + (size_t)BL_ * C_;
  f16* Vh = QKVh + (size_t)2 * BL_ * C_;
  f16* ah = QKVh;                    // reuse Qh region after phi/qprobe done
  f16* phiQ = phiQK;
  f16* phiK = phiQK + (size_t)BL_ * C_;
  f16* mbuf = phiQK;                 // reuse after attn GEMM + bottom done

  dim3 blk(256);

  pack_params<<<6, blk, 0, stream>>>(bq, bk, bv, gq, gk, gv, betaq, betak, betav,
                                     bkq, bkk, bqkv, gqkv, betaqkv, bphi);

  // weight transposes to [N,K] f16 (WqkvT = [Wq;Wk;Wv] rows)
  transpose_w<<<dim3(C_ / 32, C_ / 32), blk, 0, stream>>>(Wq, WqkvT, C_, C_);
  transpose_w<<<dim3(C_ / 32, C_ / 32), blk, 0, stream>>>(Wk, WqkvT + (size_t)C_ * C_, C_, C_);
  transpose_w<<<dim3(C_ / 32, C_ / 32), blk, 0, stream>>>(Wv, WqkvT + (size_t)2 * C_ * C_, C_, C_);
  transpose_w<<<dim3(C_ / 32, C_ / 32), blk, 0, stream>>>(Wkq, WkqT, C_, C_);
  transpose_w<<<dim3(C_ / 32, C_ / 32), blk, 0, stream>>>(Wkk, WkkT, C_, C_);
  transpose_w<<<dim3(MLP_ / 32, C_ / 32), blk, 0, stream>>>(W1, W1T, C_, MLP_);
  transpose_w<<<dim3(C_ / 32, MLP_ / 32), blk, 0, stream>>>(W2, W2T, MLP_, C_);

  transpose_x<<<dim3(L_ / 32, C_ / 32, B_), blk, 0, stream>>>(x, xf);

  // fused QKV projection: [16384,512] @ [512,1536] -> tmpqkv f16
  gemm64<5><<<dim3(BL_ / 128, 1536 / 128), blk, 0, stream>>>(
      xf, WqkvT, bqkv, tmpqkv, 1536, C_, nullptr, 0, 0, 0, 0, 0);
  // LN all three in one pass: rows [49152][512] -> Qh/Kh/Vh
  ln16<<<3 * BL_ / 4, blk, 0, stream>>>(tmpqkv, gqkv, betaqkv, QKVh, 1);

  hipMemsetAsync(qp, 0, (size_t)B_ * C_ * 4, stream);
  qprobe2<<<BL_ / 64, blk, 0, stream>>>(Qh, qp);

  // phi projections, z-batched (z=0: Qh@Wkq->phiQ, z=1: Kh@Wkk->phiK)
  gemm64<1><<<dim3(BL_ / 128, C_ / 128, 2), blk, 0, stream>>>(
      Qh, WkqT, bphi, phiQ, C_, C_, nullptr,
      (long long)BL_ * C_, (long long)C_ * C_, (long long)BL_ * C_, (long long)C_, 0);

  logits_kernel<<<BL_ / 4, blk, 0, stream>>>(Kh, qp, score);
  softmax_kernel<<<B_ * H_, blk, 0, stream>>>(score);

  ksum_init<<<(B_ * H_ * DH_) / 256, blk, 0, stream>>>(score, bkk, ksum);
  kv_part_kernel<<<dim3(16, B_ * H_), blk, 0, stream>>>(phiK, Vh, score, kvp, ksum);

  build_bd<<<(B_ * C_ * C_) / 256, blk, 0, stream>>>(kvp, BD);
  bottom_kernel<<<BL_ / 4, blk, 0, stream>>>(phiQ, ksum, bot);

  // attention out = (phiQ @ blockdiag(kv)) / (phiQ . ksum + 1e-6), z over batch
  gemm64<3><<<dim3(L_ / 128, C_ / 128, B_), blk, 0, stream>>>(
      phiQ, BD, nullptr, tmpA, C_, C_, bot,
      (long long)L_ * C_, (long long)C_ * C_, (long long)L_ * C_, 0, (long long)L_ * H_);

  ln16<<<BL_ / 4, blk, 0, stream>>>(tmpA, g_at, b_at, ah, 0);

  // MLP
  gemm64<2><<<dim3(BL_ / 128, MLP_ / 128), blk, 0, stream>>>(
      ah, W1T, b1, h1, MLP_, C_, nullptr, 0, 0, 0, 0, 0);
  gemm64<5><<<dim3(BL_ / 128, C_ / 128), blk, 0, stream>>>(
      h1, W2T, b2, mbuf, C_, MLP_, nullptr, 0, 0, 0, 0, 0);

  final_add<<<dim3(L_ / 32, C_ / 32, B_), blk, 0, stream>>>(ah, mbuf, x, out);
}

// Round 4
// 408.381 us; speedup vs baseline: 1.6468x; 1.0712x over previous
//
#include <hip/hip_runtime.h>
#include <math.h>

#define B_ 4
#define C_ 512
#define L_ 4096
#define H_ 8
#define DH_ 64
#define MLP_ 2048
#define BL_ (B_*L_)      // 16384
#define LK_ (L_+1)       // 4097

typedef _Float16 f16;
typedef _Float16 f16x8 __attribute__((ext_vector_type(8)));
typedef _Float16 f16x4 __attribute__((ext_vector_type(4)));
typedef float f32x4 __attribute__((ext_vector_type(4)));

// async global->LDS, 16B per lane (m97 pattern)
__device__ __forceinline__ void gl16(void* lds, const void* g) {
  __builtin_amdgcn_global_load_lds((const __attribute__((address_space(1))) void*)g,
                                   (__attribute__((address_space(3))) void*)lds,
                                   16, 0, 0);
}

__device__ __forceinline__ float frcp(float x) { return __builtin_amdgcn_rcpf(x); }

// ---------------------------------------------------------------- transposes
// z-merged 512x512 weight transposes; outputs contiguous at dst + z*C*C
__global__ __launch_bounds__(256) void transpose_w5(const float* __restrict__ Wq,
                                                    const float* __restrict__ Wk,
                                                    const float* __restrict__ Wv,
                                                    const float* __restrict__ Wkq,
                                                    const float* __restrict__ Wkk,
                                                    f16* __restrict__ dst) {
  int z = blockIdx.z;
  const float* W = (z == 0) ? Wq : (z == 1) ? Wk : (z == 2) ? Wv : (z == 3) ? Wkq : Wkk;
  f16* Wt = dst + (size_t)z * C_ * C_;
  __shared__ float tile[32][33];
  int n0 = blockIdx.x * 32, k0 = blockIdx.y * 32;
  int tx = threadIdx.x & 31, ty = threadIdx.x >> 5;
#pragma unroll
  for (int i = 0; i < 4; ++i)
    tile[ty + i * 8][tx] = W[(size_t)(k0 + ty + i * 8) * C_ + n0 + tx];
  __syncthreads();
#pragma unroll
  for (int i = 0; i < 4; ++i)
    Wt[(size_t)(n0 + ty + i * 8) * C_ + k0 + tx] = (f16)tile[tx][ty + i * 8];
}

__global__ __launch_bounds__(256) void transpose_w(const float* __restrict__ W,
                                                   f16* __restrict__ Wt, int K, int N) {
  __shared__ float tile[32][33];
  int n0 = blockIdx.x * 32, k0 = blockIdx.y * 32;
  int tx = threadIdx.x & 31, ty = threadIdx.x >> 5;
#pragma unroll
  for (int i = 0; i < 4; ++i)
    tile[ty + i * 8][tx] = W[(size_t)(k0 + ty + i * 8) * N + n0 + tx];
  __syncthreads();
#pragma unroll
  for (int i = 0; i < 4; ++i)
    Wt[(size_t)(n0 + ty + i * 8) * K + k0 + tx] = (f16)tile[tx][ty + i * 8];
}

__global__ __launch_bounds__(256) void transpose_x(const float* __restrict__ x,
                                                   f16* __restrict__ xf) {
  __shared__ float tile[32][33];
  int b = blockIdx.z;
  int l0 = blockIdx.x * 32, c0 = blockIdx.y * 32;
  int tx = threadIdx.x & 31, ty = threadIdx.x >> 5;
#pragma unroll
  for (int i = 0; i < 4; ++i)
    tile[ty + i * 8][tx] = x[((size_t)b * C_ + c0 + ty + i * 8) * L_ + l0 + tx];
  __syncthreads();
#pragma unroll
  for (int i = 0; i < 4; ++i)
    xf[((size_t)b * L_ + l0 + ty + i * 8) * C_ + c0 + tx] = (f16)tile[tx][ty + i * 8];
}

// ------------------------------------------------- pack small param vectors
__global__ __launch_bounds__(256) void pack_params(
    const float* bq, const float* bk, const float* bv,
    const float* gq, const float* gk, const float* gv,
    const float* betaq, const float* betak, const float* betav,
    const float* bkq, const float* bkk,
    float* bqkv, float* gqkv, float* betaqkv, float* bphi) {
  int i = blockIdx.x * 256 + threadIdx.x;  // 0..1535
  int w = i >> 9, c = i & 511;
  bqkv[i]    = (w == 0 ? bq : (w == 1 ? bk : bv))[c];
  gqkv[i]    = (w == 0 ? gq : (w == 1 ? gk : gv))[c];
  betaqkv[i] = (w == 0 ? betaq : (w == 1 ? betak : betav))[c];
  if (i < 1024) bphi[i] = (i < 512) ? bkq[i] : bkk[i - 512];
}

// ---------------------------------------------------------------- GEMM (MFMA)
// C[M,N](f16) = act(A[M,K] @ Bt[N,K]^T + bias)
// BK=64, double-buffered LDS (prefetch after barrier -> loads overlap MFMA),
// XOR-swizzled k-chunks (conflict-free ds_read_b128), LDS-transposed epilogue.
// EPI: 1 tanh(v)+1   2 gelu (tanh approx)   3 v/(Bot+1e-6)   5 plain bias
//      6 plain bias + a-residual + transposed f32 out (+x)    [MLP-down fusion]
template <int EPI>
__global__ __launch_bounds__(256, 2) void gemm64(const f16* __restrict__ A,
                                                 const f16* __restrict__ Bt,
                                                 const float* __restrict__ bias,
                                                 f16* __restrict__ Ch,
                                                 int N, int K,
                                                 const float* __restrict__ Bot,
                                                 const f16* __restrict__ Ares,
                                                 const float* __restrict__ Xres,
                                                 float* __restrict__ Fout,
                                                 long long zA, long long zB,
                                                 long long zC, long long zBias,
                                                 long long zBot) {
  __shared__ f16 smem[2 * 128 * 128];  // 64 KB: [As|Bs] x 2 buffers; epi: [128][128]
  A  += (size_t)blockIdx.z * zA;
  Bt += (size_t)blockIdx.z * zB;
  if (EPI != 6) Ch += (size_t)blockIdx.z * zC;
  if (EPI == 3) Bot += (size_t)blockIdx.z * zBot;
  else          bias += (size_t)blockIdx.z * zBias;

  const int tid = threadIdx.x;
  const int lane = tid & 63, wv = tid >> 6;
  const int wm = wv >> 1, wn = wv & 1;
  const int bm = blockIdx.x * 128, bn = blockIdx.y * 128;
  const int l15 = lane & 15, q = lane >> 4;

  // staging: inst p covers rows p*32+(tid>>3); lane fetches global k-chunk
  // (tid&7)^(row&7) into LDS slot tid*16B -> LDS[r][c] holds chunk c^(r&7)
  const int srow = tid >> 3;
  const int schunk = (tid & 7) ^ (srow & 7);
  const f16* pa = A + (size_t)(bm + srow) * K + schunk * 8;
  const f16* pb = Bt + (size_t)(bn + srow) * K + schunk * 8;
  f16* la = smem + tid * 8;
  f16* lb = smem + 8192 + tid * 8;
  const int sw0 = (q ^ (lane & 7)) * 8;        // frag read swizzle, ks=0
  const int sw1 = ((4 + q) ^ (lane & 7)) * 8;  // ks=1

  f32x4 acc[4][4] = {};

  // prologue: fill buffer 0
#pragma unroll
  for (int p = 0; p < 4; ++p) gl16(la + p * 2048, pa + (size_t)p * 32 * K);
#pragma unroll
  for (int p = 0; p < 4; ++p) gl16(lb + p * 2048, pb + (size_t)p * 32 * K);

  int cur = 0;
  for (int k0 = 0; k0 < K; k0 += 64) {
    __syncthreads();                 // vmcnt(0) drain: buf(cur) staged; buf(nxt) readers done
    const int nxt = cur ^ 1;
    if (k0 + 64 < K) {               // prefetch next chunk into the other buffer
#pragma unroll
      for (int p = 0; p < 4; ++p) gl16(la + nxt * 16384 + p * 2048, pa + (size_t)p * 32 * K + k0 + 64);
#pragma unroll
      for (int p = 0; p < 4; ++p) gl16(lb + nxt * 16384 + p * 2048, pb + (size_t)p * 32 * K + k0 + 64);
    }
    const f16* As = smem + cur * 16384;
    const f16* Bs = As + 8192;
#pragma unroll
    for (int ks = 0; ks < 2; ++ks) {
      const int sw = ks ? sw1 : sw0;
      f16x8 af[4], bf[4];
#pragma unroll
      for (int i = 0; i < 4; ++i)
        af[i] = *(const f16x8*)&As[(wm * 64 + i * 16 + l15) * 64 + sw];
#pragma unroll
      for (int j = 0; j < 4; ++j)
        bf[j] = *(const f16x8*)&Bs[(wn * 64 + j * 16 + l15) * 64 + sw];
#pragma unroll
      for (int i = 0; i < 4; ++i)
#pragma unroll
        for (int j = 0; j < 4; ++j)
          acc[i][j] = __builtin_amdgcn_mfma_f32_16x16x32_f16(af[i], bf[j], acc[i][j], 0, 0, 0);
    }
    cur = nxt;
  }

  // ---- epilogue: act -> smem[0..16K) (col-chunk XOR swizzle)
  __syncthreads();
#pragma unroll
  for (int j = 0; j < 4; ++j) {
    int lc = wn * 64 + j * 16 + l15;
    float bb = (EPI == 3) ? 0.f : bias[bn + lc];
#pragma unroll
    for (int i = 0; i < 4; ++i) {
#pragma unroll
      for (int r = 0; r < 4; ++r) {
        int lr = wm * 64 + i * 16 + q * 4 + r;
        float v = acc[i][j][r] + bb;
        if (EPI == 1) {
          v = 2.0f * frcp(1.0f + __expf(-2.0f * v));      // tanh(v)+1
        } else if (EPI == 2) {
          v = v * frcp(1.0f + __expf(-1.5957691f * (v + 0.044715f * v * v * v)));
        } else if (EPI == 3) {
          v = v * frcp(Bot[(size_t)(bm + lr) * H_ + ((bn + lc) >> 6)] + 1e-6f);
        }
        smem[lr * 128 + ((((lc >> 3) ^ (lr & 15)) << 3) | (lc & 7))] = (f16)v;
      }
    }
  }
  __syncthreads();

  if (EPI != 6) {
    // coalesced f16x8 row store
#pragma unroll
    for (int p = 0; p < 8; ++p) {
      int idx = p * 256 + tid;
      int row = idx >> 4, ch = idx & 15;
      f16x8 vv = *(const f16x8*)&smem[row * 128 + ((ch ^ (row & 15)) << 3)];
      *(f16x8*)&Ch[(size_t)(bm + row) * N + bn + ch * 8] = vv;
    }
  } else {
    // add a-residual (row-coalesced RMW in LDS)
#pragma unroll
    for (int p = 0; p < 8; ++p) {
      int idx = p * 256 + tid;
      int row = idx >> 4, ch = idx & 15;
      f16x8 av = *(const f16x8*)&Ares[(size_t)(bm + row) * C_ + bn + ch * 8];
      f16* sp = &smem[row * 128 + ((ch ^ (row & 15)) << 3)];
      f16x8 sv = *(const f16x8*)sp;
#pragma unroll
      for (int jj = 0; jj < 8; ++jj) sv[jj] = (f16)((float)sv[jj] + (float)av[jj]);
      *(f16x8*)sp = sv;
    }
    __syncthreads();
    // transposed f32 write: out[b][c][l] = tile[l][c] + x[b][c][l]
    int c = tid & 127, lh = tid >> 7;
    int b = bm >> 12, lbase = (bm & 4095) + lh * 64;
    const float* xp = Xres + ((size_t)b * C_ + bn + c) * L_ + lbase;
    float* op = Fout + ((size_t)b * C_ + bn + c) * L_ + lbase;
    int chi = c >> 3, clo = c & 7;
#pragma unroll
    for (int s = 0; s < 16; ++s) {
      int l = lh * 64 + s * 4;
      float4 xv = *(const float4*)(xp + s * 4);
      float4 r;
      r.x = (float)smem[(l + 0) * 128 + (((chi ^ ((l + 0) & 15)) << 3) | clo)] + xv.x;
      r.y = (float)smem[(l + 1) * 128 + (((chi ^ ((l + 1) & 15)) << 3) | clo)] + xv.y;
      r.z = (float)smem[(l + 2) * 128 + (((chi ^ ((l + 2) & 15)) << 3) | clo)] + xv.z;
      r.w = (float)smem[(l + 3) * 128 + (((chi ^ ((l + 3) & 15)) << 3) | clo)] + xv.w;
      *(float4*)(op + s * 4) = r;
    }
  }
}

// ---------------------------------------------------------------- LayerNorm (f16 in/out)
// threeway=1: X is [49152][512] rows (token*3+which); out which*BL + token.
__global__ __launch_bounds__(256) void ln16(const f16* __restrict__ X,
                                            const float* __restrict__ g,
                                            const float* __restrict__ bta,
                                            f16* __restrict__ Y, int threeway) {
  int wv = threadIdx.x >> 6, lane = threadIdx.x & 63;
  int r = blockIdx.x * 4 + wv;
  int token = r, which = 0;
  if (threeway) { token = r / 3; which = r - token * 3; }
  const f16* xr = X + (size_t)r * C_;
  f16x8 v = *(const f16x8*)(xr + lane * 8);
  float vals[8];
  float s = 0.f, s2 = 0.f;
#pragma unroll
  for (int j = 0; j < 8; ++j) { vals[j] = (float)v[j]; s += vals[j]; s2 += vals[j] * vals[j]; }
#pragma unroll
  for (int m_ = 1; m_ < 64; m_ <<= 1) { s += __shfl_xor(s, m_); s2 += __shfl_xor(s2, m_); }
  float mu = s * (1.f / C_);
  float var = s2 * (1.f / C_) - mu * mu;
  float rstd = rsqrtf(var + 1e-5f);
  const float* gp = g + which * C_;
  const float* bp = bta + which * C_;
  f16x8 o;
#pragma unroll
  for (int j = 0; j < 8; ++j) {
    int c = lane * 8 + j;
    o[j] = (f16)((vals[j] - mu) * rstd * gp[c] + bp[c]);
  }
  *(f16x8*)(Y + ((size_t)which * BL_ + token) * C_ + lane * 8) = o;
}

// ---------------------------------------------------------------- q_probe
__global__ __launch_bounds__(256) void qprobe2(const f16* __restrict__ Q,
                                               float* __restrict__ qp) {
  int blk = blockIdx.x;
  int b = blk >> 6;             // 64 blocks per batch
  int r0 = blk * 64;
  int t = threadIdx.x;
  int c8 = (t & 63) * 8, rg = t >> 6;
  float s[8] = {0.f, 0.f, 0.f, 0.f, 0.f, 0.f, 0.f, 0.f};
#pragma unroll
  for (int i = 0; i < 16; ++i) {
    const f16* row = Q + ((size_t)r0 + rg + i * 4) * C_ + c8;
    f16x8 v = *(const f16x8*)row;
#pragma unroll
    for (int j = 0; j < 8; ++j) s[j] += (float)v[j];
  }
  __shared__ float red[4][520];
#pragma unroll
  for (int j = 0; j < 8; ++j) red[rg][c8 + j] = s[j];
  __syncthreads();
  int c = t * 2;
  float a0 = red[0][c] + red[1][c] + red[2][c] + red[3][c];
  float a1 = red[0][c + 1] + red[1][c + 1] + red[2][c + 1] + red[3][c + 1];
  atomicAdd(&qp[b * C_ + c], a0);
  atomicAdd(&qp[b * C_ + c + 1], a1);
}

// ---------------------------------------------------------------- score logits
__global__ __launch_bounds__(256) void logits_kernel(const f16* __restrict__ Kh,
                                                     const float* __restrict__ qp,
                                                     float* __restrict__ score) {
  int wv = threadIdx.x >> 6, lane = threadIdx.x & 63;
  int token = blockIdx.x * 4 + wv;  // b*L + l
  int b = token >> 12;
  int l = token & (L_ - 1);
  const f16* row = Kh + (size_t)token * C_;
  int h = lane >> 3, j0 = (lane & 7) * 8;
  const float* qph = qp + b * C_ + h * DH_ + j0;
  float p = 0.f;
#pragma unroll
  for (int j = 0; j < 8; ++j) p += qph[j] * (float)row[h * DH_ + j0 + j];
  p += __shfl_xor(p, 1); p += __shfl_xor(p, 2); p += __shfl_xor(p, 4);
  if ((lane & 7) == 0)
    score[((size_t)b * H_ + h) * LK_ + 1 + l] = p * (1.f / L_) * 0.125f;  // /L mean, /sqrt(64)
}

__global__ __launch_bounds__(256) void softmax_kernel(float* __restrict__ score) {
  int bh = blockIdx.x, t = threadIdx.x;
  float* s = score + (size_t)bh * LK_;
  __shared__ float red[256];
  float mx = 0.f;  // logit[0] == 0 participates
  for (int i = t; i < L_; i += 256) mx = fmaxf(mx, s[1 + i]);
  red[t] = mx; __syncthreads();
  for (int k = 128; k; k >>= 1) { if (t < k) red[t] = fmaxf(red[t], red[t + k]); __syncthreads(); }
  mx = red[0]; __syncthreads();
  float sum = (t == 0) ? expf(-mx) : 0.f;
  for (int i = t; i < L_; i += 256) { float e = expf(s[1 + i] - mx); s[1 + i] = e; sum += e; }
  red[t] = sum; __syncthreads();
  for (int k = 128; k; k >>= 1) { if (t < k) red[t] += red[t + k]; __syncthreads(); }
  float inv = 1.f / red[0];
  __syncthreads();
  for (int i = t; i < L_; i += 256) s[1 + i] *= inv;
  if (t == 0) s[0] = expf(-mx) * inv;
}

// ---------------------------------------------------------------- kv / ksum
__global__ __launch_bounds__(256) void ksum_init(const float* __restrict__ score,
                                                 const float* __restrict__ bkk,
                                                 float* __restrict__ ksum) {
  int i = blockIdx.x * 256 + threadIdx.x;  // 0..2047
  int bh = i >> 6, d = i & 63, h = bh & 7;
  float pk0 = tanhf(bkk[h * DH_ + d]) + 1.f;
  ksum[i] = score[(size_t)bh * LK_] * pk0;
}

// kv partials: grid (16 parts, 32 bh), 256 thr. Each block: 256 l-rows.
#define PIDX(l, c) ((l) * 68 + (c))
#define AIDX(d, e) ((d) * 68 + (e) + ((((d) >> 3)) << 2))   // bank-skewed
__global__ __launch_bounds__(256, 2) void kv_part_kernel(const f16* __restrict__ phiK,
                                                         const f16* __restrict__ Vh,
                                                         const float* __restrict__ score,
                                                         float* __restrict__ kvp,
                                                         float* __restrict__ ksum) {
  __shared__ float sm0[4416];   // weighted phiK chunk  [64][68] / later accum
  __shared__ float sm1[4416];   // V chunk              [64][68] / later ksum red
  int bh = blockIdx.y, b = bh >> 3, h = bh & 7;
  int part = blockIdx.x;
  int l0 = part * 256;
  int t = threadIdx.x, lane = t & 63, wv = t >> 6;
  int R = (lane >> 3) * 8, Cc = (lane & 7) * 8;
  float acc[8][8] = {};
  float ks[8] = {0.f, 0.f, 0.f, 0.f, 0.f, 0.f, 0.f, 0.f};

  for (int c = 0; c < 4; ++c) {      // chunks of 64 l
    int lc = l0 + c * 64;
    __syncthreads();                 // prior chunk's reads done
#pragma unroll
    for (int p = 0; p < 4; ++p) {
      int l = p * 16 + (t >> 4);
      int c4 = (t & 15) * 4;
      size_t grow = ((size_t)b * L_ + lc + l) * C_ + h * DH_ + c4;
      float w = score[(size_t)bh * LK_ + 1 + lc + l];
      f16x4 pk = *(const f16x4*)(phiK + grow);
      f16x4 vvv = *(const f16x4*)(Vh + grow);
      sm0[PIDX(l, c4) + 0] = w * (float)pk[0];
      sm0[PIDX(l, c4) + 1] = w * (float)pk[1];
      sm0[PIDX(l, c4) + 2] = w * (float)pk[2];
      sm0[PIDX(l, c4) + 3] = w * (float)pk[3];
      sm1[PIDX(l, c4) + 0] = (float)vvv[0];
      sm1[PIDX(l, c4) + 1] = (float)vvv[1];
      sm1[PIDX(l, c4) + 2] = (float)vvv[2];
      sm1[PIDX(l, c4) + 3] = (float)vvv[3];
    }
    __syncthreads();
#pragma unroll
    for (int i = 0; i < 16; ++i) {   // wave wv owns rows wv*16..+15
      int ll = wv * 16 + i;
      float4 a0 = *(const float4*)&sm0[PIDX(ll, R)];
      float4 a1 = *(const float4*)&sm0[PIDX(ll, R + 4)];
      float4 b0 = *(const float4*)&sm1[PIDX(ll, Cc)];
      float4 b1 = *(const float4*)&sm1[PIDX(ll, Cc + 4)];
      float av[8] = {a0.x, a0.y, a0.z, a0.w, a1.x, a1.y, a1.z, a1.w};
      float bv2[8] = {b0.x, b0.y, b0.z, b0.w, b1.x, b1.y, b1.z, b1.w};
#pragma unroll
      for (int ii = 0; ii < 8; ++ii)
#pragma unroll
        for (int jj = 0; jj < 8; ++jj) acc[ii][jj] += av[ii] * bv2[jj];
      if ((lane & 7) == 0) {
#pragma unroll
        for (int ii = 0; ii < 8; ++ii) ks[ii] += av[ii];
      }
    }
  }

  __syncthreads();                   // done with staging buffers
  if ((lane & 7) == 0) {
#pragma unroll
    for (int i = 0; i < 8; ++i) sm1[wv * 64 + R + i] = ks[i];
  }
  for (int w = 0; w < 4; ++w) {
    if (wv == w) {
#pragma unroll
      for (int i = 0; i < 8; ++i) {
        float* p0 = &sm0[AIDX(R + i, Cc)];
        if (w == 0) {
          *(float4*)p0 = make_float4(acc[i][0], acc[i][1], acc[i][2], acc[i][3]);
          *(float4*)(p0 + 4) = make_float4(acc[i][4], acc[i][5], acc[i][6], acc[i][7]);
        } else {
          float4 o0 = *(const float4*)p0, o1 = *(const float4*)(p0 + 4);
          o0.x += acc[i][0]; o0.y += acc[i][1]; o0.z += acc[i][2]; o0.w += acc[i][3];
          o1.x += acc[i][4]; o1.y += acc[i][5]; o1.z += acc[i][6]; o1.w += acc[i][7];
          *(float4*)p0 = o0;
          *(float4*)(p0 + 4) = o1;
        }
      }
    }
    __syncthreads();
  }
  if (t < 64) {
    float s = sm1[t] + sm1[64 + t] + sm1[128 + t] + sm1[192 + t];
    atomicAdd(&ksum[bh * 64 + t], s);
  }
  float* dst = kvp + ((size_t)bh * 16 + part) * 4096;
#pragma unroll
  for (int i = 0; i < 16; ++i) {
    int idx = i * 256 + t;           // idx = e*64+d
    dst[idx] = sm0[AIDX(idx & 63, idx >> 6)];
  }
}

// block-diagonal kv as Bt[N=512][K=512] per batch (f16), summing 16 partials
__global__ __launch_bounds__(256) void build_bd(const float* __restrict__ kvp,
                                                f16* __restrict__ BD) {
  size_t i = (size_t)blockIdx.x * 256 + threadIdx.x;  // over 4*512*512
  int b = (int)(i >> 18);
  int nk = (int)(i & 262143);
  int n = nk >> 9, k = nk & 511;
  int hn = n >> 6, hk = k >> 6;
  float v = 0.f;
  if (hn == hk) {
    const float* p = kvp + ((size_t)(b * H_ + hn) * 16) * 4096 + (n & 63) * 64 + (k & 63);
#pragma unroll
    for (int pp = 0; pp < 16; ++pp) v += p[pp * 4096];
  }
  BD[i] = (f16)v;
}

// bottom[b*L*H]: phiQ . ksum per (token, head)
__global__ __launch_bounds__(256) void bottom_kernel(const f16* __restrict__ phiQ,
                                                     const float* __restrict__ ksum,
                                                     float* __restrict__ bot) {
  int wv = threadIdx.x >> 6, lane = threadIdx.x & 63;
  int token = blockIdx.x * 4 + wv;  // b*L + l
  int b = token >> 12;
  const f16* row = phiQ + (size_t)token * C_;
  int h = lane >> 3, j0 = (lane & 7) * 8;
  const float* ks = ksum + (b * H_ + h) * 64 + j0;
  float p = 0.f;
#pragma unroll
  for (int j = 0; j < 8; ++j) p += ks[j] * (float)row[h * DH_ + j0 + j];
  p += __shfl_xor(p, 1); p += __shfl_xor(p, 2); p += __shfl_xor(p, 4);
  if ((lane & 7) == 0) bot[(size_t)token * H_ + h] = p;
}

// ---------------------------------------------------------------- launch
extern "C" void kernel_launch(void* const* d_in, const int* in_sizes, int n_in,
                              void* d_out, int out_size, void* d_ws, size_t ws_size,
                              hipStream_t stream) {
  (void)in_sizes; (void)n_in; (void)out_size; (void)ws_size;
  const float* x     = (const float*)d_in[0];
  const float* Wq    = (const float*)d_in[1];
  const float* bq    = (const float*)d_in[2];
  const float* gq    = (const float*)d_in[3];
  const float* betaq = (const float*)d_in[4];
  const float* Wk    = (const float*)d_in[5];
  const float* bk    = (const float*)d_in[6];
  const float* gk    = (const float*)d_in[7];
  const float* betak = (const float*)d_in[8];
  const float* Wv    = (const float*)d_in[9];
  const float* bv    = (const float*)d_in[10];
  const float* gv    = (const float*)d_in[11];
  const float* betav = (const float*)d_in[12];
  const float* Wkq   = (const float*)d_in[13];
  const float* bkq   = (const float*)d_in[14];
  const float* Wkk   = (const float*)d_in[15];
  const float* bkk   = (const float*)d_in[16];
  const float* g_at  = (const float*)d_in[17];
  const float* b_at  = (const float*)d_in[18];
  const float* W1    = (const float*)d_in[19];
  const float* b1    = (const float*)d_in[20];
  const float* W2    = (const float*)d_in[21];
  const float* b2    = (const float*)d_in[22];
  float* out = (float*)d_out;

  char* ws = (char*)d_ws;
  size_t off = 0;
  auto alloc = [&](size_t bytes) -> void* {
    void* p = ws + off;
    off += (bytes + 255) & ~(size_t)255;
    return p;
  };
  // U1: tmpqkv(48MB) -> tmpA(16MB) -> h1(64MB), temporally disjoint
  f16* U1    = (f16*)alloc((size_t)BL_ * MLP_ * 2);       // 64 MB
  f16* QKVh  = (f16*)alloc((size_t)3 * BL_ * C_ * 2);     // 48 MB (Qh|Kh|Vh; ah reuses Qh)
  f16* phiQK = (f16*)alloc((size_t)2 * BL_ * C_ * 2);     // 32 MB (phiQ|phiK)
  f16* xf    = (f16*)alloc((size_t)BL_ * C_ * 2);         // 16 MB
  f16* WqkvT = (f16*)alloc((size_t)3 * C_ * C_ * 2);      // Wq|Wk|Wv transposed
  f16* WkqT  = (f16*)alloc((size_t)C_ * C_ * 2);          // contiguous after WqkvT
  f16* WkkT  = (f16*)alloc((size_t)C_ * C_ * 2);          // contiguous after WkqT
  f16* W1T   = (f16*)alloc((size_t)C_ * MLP_ * 2);
  f16* W2T   = (f16*)alloc((size_t)MLP_ * C_ * 2);
  f16* BD    = (f16*)alloc((size_t)B_ * C_ * C_ * 2);
  float* score = (float*)alloc((size_t)B_ * H_ * LK_ * 4);
  float* qp    = (float*)alloc((size_t)B_ * C_ * 4);
  float* kvp   = (float*)alloc((size_t)B_ * H_ * 16 * 4096 * 4);
  float* ksum  = (float*)alloc((size_t)B_ * H_ * DH_ * 4);
  float* bot   = (float*)alloc((size_t)BL_ * H_ * 4);
  float* bqkv    = (float*)alloc(1536 * 4);
  float* gqkv    = (float*)alloc(1536 * 4);
  float* betaqkv = (float*)alloc(1536 * 4);
  float* bphi    = (float*)alloc(1024 * 4);

  f16* tmpqkv = U1;                  // [49152][512] f16
  f16* tmpA   = U1;                  // [16384][512] f16
  f16* h1     = U1;                  // [16384][2048] f16
  f16* Qh = QKVh;
  f16* Kh = QKVh + (size_t)BL_ * C_;
  f16* Vh = QKVh + (size_t)2 * BL_ * C_;
  f16* ah = QKVh;                    // reuse Qh region after phi/qprobe done
  f16* phiQ = phiQK;
  f16* phiK = phiQK + (size_t)BL_ * C_;

  dim3 blk(256);

  pack_params<<<6, blk, 0, stream>>>(bq, bk, bv, gq, gk, gv, betaq, betak, betav,
                                     bkq, bkk, bqkv, gqkv, betaqkv, bphi);

  // weight transposes to [N,K] f16 (5x 512x512 in one z-launch; outputs contiguous)
  transpose_w5<<<dim3(16, 16, 5), blk, 0, stream>>>(Wq, Wk, Wv, Wkq, Wkk, WqkvT);
  transpose_w<<<dim3(MLP_ / 32, C_ / 32), blk, 0, stream>>>(W1, W1T, C_, MLP_);
  transpose_w<<<dim3(C_ / 32, MLP_ / 32), blk, 0, stream>>>(W2, W2T, MLP_, C_);

  transpose_x<<<dim3(L_ / 32, C_ / 32, B_), blk, 0, stream>>>(x, xf);

  // fused QKV projection: [16384,512] @ [512,1536] -> tmpqkv f16
  gemm64<5><<<dim3(BL_ / 128, 1536 / 128), blk, 0, stream>>>(
      xf, WqkvT, bqkv, tmpqkv, 1536, C_, nullptr, nullptr, nullptr, nullptr, 0, 0, 0, 0, 0);
  // LN all three in one pass: rows [49152][512] -> Qh/Kh/Vh
  ln16<<<3 * BL_ / 4, blk, 0, stream>>>(tmpqkv, gqkv, betaqkv, QKVh, 1);

  hipMemsetAsync(qp, 0, (size_t)B_ * C_ * 4, stream);
  qprobe2<<<BL_ / 64, blk, 0, stream>>>(Qh, qp);

  // phi projections, z-batched (z=0: Qh@Wkq->phiQ, z=1: Kh@Wkk->phiK)
  gemm64<1><<<dim3(BL_ / 128, C_ / 128, 2), blk, 0, stream>>>(
      Qh, WkqT, bphi, phiQ, C_, C_, nullptr, nullptr, nullptr, nullptr,
      (long long)BL_ * C_, (long long)C_ * C_, (long long)BL_ * C_, (long long)C_, 0);

  logits_kernel<<<BL_ / 4, blk, 0, stream>>>(Kh, qp, score);
  softmax_kernel<<<B_ * H_, blk, 0, stream>>>(score);

  ksum_init<<<(B_ * H_ * DH_) / 256, blk, 0, stream>>>(score, bkk, ksum);
  kv_part_kernel<<<dim3(16, B_ * H_), blk, 0, stream>>>(phiK, Vh, score, kvp, ksum);

  build_bd<<<(B_ * C_ * C_) / 256, blk, 0, stream>>>(kvp, BD);
  bottom_kernel<<<BL_ / 4, blk, 0, stream>>>(phiQ, ksum, bot);

  // attention out = (phiQ @ blockdiag(kv)) / (phiQ . ksum + 1e-6), z over batch
  gemm64<3><<<dim3(L_ / 128, C_ / 128, B_), blk, 0, stream>>>(
      phiQ, BD, nullptr, tmpA, C_, C_, bot, nullptr, nullptr, nullptr,
      (long long)L_ * C_, (long long)C_ * C_, (long long)L_ * C_, 0, (long long)L_ * H_);

  ln16<<<BL_ / 4, blk, 0, stream>>>(tmpA, g_at, b_at, ah, 0);

  // MLP up
  gemm64<2><<<dim3(BL_ / 128, MLP_ / 128), blk, 0, stream>>>(
      ah, W1T, b1, h1, MLP_, C_, nullptr, nullptr, nullptr, nullptr, 0, 0, 0, 0, 0);
  // MLP down fused with residual-add + transpose + x-add -> out
  gemm64<6><<<dim3(BL_ / 128, C_ / 128), blk, 0, stream>>>(
      h1, W2T, b2, nullptr, C_, MLP_, nullptr, ah, x, out, 0, 0, 0, 0, 0);
}